// Round 5
// baseline (2015.098 us; speedup 1.0000x reference)
//
#include <hip/hip_runtime.h>

#define NN 20000
#define NE 640000
#define NBUK 79  // ceil(20000/256) buckets of 256 nodes

// Self-probe: int64 edge data (values < 2^31) has every odd int32 word == 0.
__device__ __forceinline__ int probe_stride(const int* __restrict__ ei32) {
  int lane = threadIdx.x & 63;
  int v = ei32[2 * lane + 1];
  unsigned long long nz = __ballot(v != 0);
  return (nz == 0ull) ? 2 : 1;
}

__device__ __forceinline__ bool maskB(int var, int o2, int o1) {
  int s = o2 + o1;
  switch (var) {
    case 0: return (o2 >= 0) && (s >= 0);
    case 1: return s >= -1;
    case 3: return s <= 1;
    case 4: return (o2 <= 0) && (s <= 0);
    default: return true;
  }
}

// ---- manual grid barrier: monotone arrival counter, device-scope ----------
// bar zeroed host-side before launch; gen = 1,2,3,... per barrier.
// Release fence + arrive; spin until all gridDim.x blocks of this generation
// arrived; acquire fence. gfx950 agent fences emit buffer_wbl2/inv sc1 which
// handle cross-XCD L2 non-coherence (G16).
__device__ __forceinline__ void gbar(int* bar, int gen) {
  __syncthreads();
  if (threadIdx.x == 0) {
    __threadfence();                 // release: flush prior writes device-wide
    atomicAdd(bar, 1);
    int target = gen * (int)gridDim.x;
    while (__hip_atomic_load(bar, __ATOMIC_ACQUIRE, __HIP_MEMORY_SCOPE_AGENT) <
           target) {
      __builtin_amdgcn_s_sleep(2);
    }
    __threadfence();                 // acquire: invalidate stale cached lines
  }
  __syncthreads();
}

struct MegaP {
  const float* x; const int* ei;
  const float* Wl1; const float* bl1; const float* Wr1;
  const float* Wl2; const float* bl2; const float* Wr2;
  const float* Wl3; const float* bl3; const float* Wr3;
  const float* Wc1; const float* bc1; const float* Wc2; const float* bc2;
  const float* Wc3; const float* bc3; const float* W2; const float* b2;
  int* rowptr; float* invdeg; int* csr; unsigned long long* ebuf;
  int* bins; int* bcur; int* bar;
  float* Wt1; float* Wt2; float* T729; float* M5T; float* beta5;
  float* Sbuf; float* c5; float* Gbuf; float* Wg; float* bg; float* c32;
  float* yzA; float* yzB; float* hA; float* wbuf; float* s1; float* s2;
  float* dout;
  int E; int N;
};

// ---------- Phase 0 unit: weight setup (0..150) + zero bins (151) -----------
__device__ __forceinline__ void ph_setup(
    int s, int tid, float* smem,
    const float* __restrict__ Wc1, const float* __restrict__ Wc2,
    const float* __restrict__ Wc3, const float* __restrict__ bc1,
    const float* __restrict__ bc2, const float* __restrict__ bc3,
    const float* __restrict__ Wl1, const float* __restrict__ Wr1,
    const float* __restrict__ Wl2, const float* __restrict__ Wr2,
    const float* __restrict__ bl2,
    float* __restrict__ T729, float* __restrict__ beta5,
    float* __restrict__ Wt1, float* __restrict__ Wt2,
    float* __restrict__ Sbuf, float* __restrict__ c5,
    int* __restrict__ rowptr, int* __restrict__ binsbuf, int E, int N) {
  if (s == 151) {
    binsbuf[tid] = 0;  // bins[128] | bcur[128]
  } else if (s == 0) {
    // ---- conv composite T729 ----
    float* W3  = smem;         // 576
    float* S9s = smem + 576;   // 5184
    float* W1s = smem + 5760;  // 576
    if (tid == 0) rowptr[N] = E;
    for (int e = tid; e < 576; e += 256) { W3[e] = Wc3[e]; W1s[e] = Wc1[e]; }
    __syncthreads();
    for (int bb = tid; bb < 576; bb += 256) {
      float acc[9];
#pragma unroll
      for (int a = 0; a < 9; ++a) acc[a] = 0.0f;
#pragma unroll 4
      for (int o = 0; o < 64; ++o) {
        float w2 = Wc2[o * 576 + bb];
#pragma unroll
        for (int a = 0; a < 9; ++a) acc[a] += W3[o * 9 + a] * w2;
      }
#pragma unroll
      for (int a = 0; a < 9; ++a) S9s[a * 576 + bb] = acc[a];
    }
    __syncthreads();
    for (int c = tid; c < 729; c += 256) {
      int kx0  = c % 3;
      int dl1e = (c / 3) % 3;
      int dl2e = (c / 9) % 3;
      int ky0  = (c / 27) % 3;
      int ky1  = (c / 81) % 3;
      int ky2  = c / 243;
      const float* s9 = &S9s[(ky2 * 3 + dl2e) * 576 + ky1 * 3 + dl1e];
      const float* w1 = &W1s[ky0 * 3 + kx0];
      float t = 0.0f;
#pragma unroll 8
      for (int i = 0; i < 64; ++i) t += s9[i * 9] * w1[i * 9];
      T729[c] = t;
    }
  } else if (s <= 5) {
    // ---- boundary beta vectors ----
    float* S2   = smem;          // 576
    float* W3b  = smem + 576;    // 576
    float* B2   = smem + 1152;   // 64
    float* part = smem + 1216;   // 256
    int var = s - 1;
    for (int e = tid; e < 576; e += 256) {
      int o = e / 9, r = e - o * 9;
      float t = 0.0f;
      for (int i = 0; i < 64; ++i) t += Wc2[o * 576 + i * 9 + r] * bc1[i];
      S2[e] = t;
      W3b[e] = Wc3[e];
    }
    if (tid < 64) B2[tid] = bc2[tid];
    __syncthreads();
    int u = tid & 63, oc = tid >> 6;
    float acc = 0.0f;
    for (int ky2 = 0; ky2 < 3; ++ky2) {
      int o2 = ky2 - 1;
      bool okA = (var == 0) ? (o2 >= 0) : (var == 4) ? (o2 <= 0) : true;
      if (!okA) continue;
      for (int dl2 = -1; dl2 <= 1; ++dl2) {
        int p = u + dl2; if ((unsigned)p >= 64u) continue;
        float sel[9];
#pragma unroll
        for (int ky1 = 0; ky1 < 3; ++ky1) {
          int o1 = ky1 - 1;
          bool mb = maskB(var, o2, o1);
#pragma unroll
          for (int dl1 = -1; dl1 <= 1; ++dl1) {
            int pq = p + dl1;
            sel[ky1 * 3 + dl1 + 1] = (mb && (unsigned)pq < 64u) ? 1.0f : 0.0f;
          }
        }
#pragma unroll 4
        for (int oo = 0; oo < 16; ++oo) {
          int o = oc * 16 + oo;
          float inner = B2[o];
#pragma unroll
          for (int r = 0; r < 9; ++r) inner += S2[o * 9 + r] * sel[r];
          acc += W3b[o * 9 + ky2 * 3 + (dl2 + 1)] * inner;
        }
      }
    }
    part[tid] = acc;
    __syncthreads();
    if (tid < 64) {
      beta5[var * 64 + tid] =
          bc3[0] + part[tid] + part[64 + tid] + part[128 + tid] + part[192 + tid];
    }
  } else {
    // ---- transposes + S-matrices + c5 ----
    int idx = (s - 6) * 256 + tid;  // 0..37119
    if (idx < 16384) {
      int w = idx >> 7, u = idx & 127;
      Wt1[idx] = (u < 64) ? Wl1[u * 128 + w] : Wr1[(u - 64) * 128 + w];
    } else if (idx < 24576) {
      int t = idx - 16384;
      int w = t >> 7, u = t & 127;
      Wt2[t] = (u < 64) ? Wl2[u * 64 + w] : Wr2[(u - 64) * 64 + w];
    } else if (idx < 36864) {
      // S2 = P·P, S1 = Q·P + P·Q, S0 = Q·Q  (P=Wl2^T, Q=Wr2^T)
      int t2 = idx - 24576;
      int m = t2 >> 12, e = t2 & 4095;
      int i = e >> 6, j = e & 63;
      float acc = 0.0f;
#pragma unroll 4
      for (int k = 0; k < 64; ++k) {
        float wlj = Wl2[j * 64 + k], wrj = Wr2[j * 64 + k];
        float wli = Wl2[k * 64 + i], wri = Wr2[k * 64 + i];
        if (m == 0) acc += wli * wlj;
        else if (m == 1) acc += wri * wlj + wli * wrj;
        else acc += wri * wrj;
      }
      Sbuf[t2] = acc;
    } else if (idx < 36928) {
      // c5 = bl2^T (P + Q + I)
      int j = idx - 36864;
      float acc = bl2[j];
      for (int i = 0; i < 64; ++i)
        acc += bl2[i] * (Wl2[j * 64 + i] + Wr2[j * 64 + i]);
      c5[j] = acc;
    }
  }
}

// ---------- Phase 1 unit: hist(0..156) | m5(157..218) | G(219..251) | gemm --
__device__ __forceinline__ void ph_one(
    int u, int tid, float* smem,
    const float* __restrict__ X, const float* __restrict__ Wt1,
    float* __restrict__ yzA,
    const int* __restrict__ ei, int* __restrict__ bins,
    const float* __restrict__ T729, float* __restrict__ M5T,
    const float* __restrict__ Sbuf, const float* __restrict__ c5,
    const float* __restrict__ Wl3, const float* __restrict__ Wr3,
    const float* __restrict__ bl3, float* __restrict__ Gbuf,
    float* __restrict__ c32, int E, int N) {
  if (u < 157) {
    // ---- histogram ----
    int* lb = (int*)smem;
    int st = probe_stride(ei);
    for (int i = tid; i < NBUK; i += 256) lb[i] = 0;
    __syncthreads();
    int e0 = u * 4096;
#pragma unroll
    for (int t = 0; t < 16; ++t) {
      int e = e0 + t * 256 + tid;
      if (e < E) atomicAdd(&lb[ei[(size_t)(E + e) * st] >> 8], 1);
    }
    __syncthreads();
    for (int i = tid; i < NBUK; i += 256)
      if (lb[i]) atomicAdd(&bins[i], lb[i]);
  } else if (u < 219) {
    // ---- M5T ----
    float* Ts = smem;  // 729
    for (int e = tid; e < 729; e += 256) Ts[e] = T729[e];
    __syncthreads();
    int idx = (u - 157) * 256 + tid;
    if (idx < 15680) {
      int jw = idx % 7;
      int uu = (idx / 7) % 64;
      int d  = (idx / 448) % 7;
      int var = idx / 3136;
      int w = uu + jw - 3;
      float acc = 0.0f;
      if (w >= 0 && w < 64) {
        for (int ky2 = 0; ky2 < 3; ++ky2) {
          int o2 = ky2 - 1;
          for (int ky1 = 0; ky1 < 3; ++ky1) {
            int o1 = ky1 - 1;
            if (!maskB(var, o2, o1)) continue;
            int o0 = (d - 3) - o2 - o1;
            if (o0 < -1 || o0 > 1) continue;
            int ky0 = o0 + 1;
            int cbase = ((ky2 * 3 + ky1) * 3 + ky0) * 27;
#pragma unroll
            for (int kx0 = 0; kx0 < 3; ++kx0) {
              int jq = jw - kx0;
              if ((unsigned)jq >= 5u) continue;
              int q = uu + jq - 2;
              if ((unsigned)q >= 64u) continue;
#pragma unroll
              for (int dl2e = 0; dl2e < 3; ++dl2e) {
                int pp = uu + dl2e - 1;
                if ((unsigned)pp >= 64u) continue;
                int dl1e = jq - dl2e;
                if ((unsigned)dl1e >= 3u) continue;
                acc += Ts[cbase + dl2e * 9 + dl1e * 3 + kx0];
              }
            }
          }
        }
      }
      if (d == 3 && jw == 3) acc += 1.0f;  // residual
      M5T[(var * 49 + d * 7 + jw) * 64 + uu] = acc;
    }
  } else if (u < 252) {
    // ---- G-matrices ----
    int bb = u - 219;
    if (bb < 32) {
      int idx = bb * 256 + tid;
      int kblk = idx >> 11;
      int rem = idx & 2047;
      int t = rem >> 5, j = rem & 31;
      const float* S2p = Sbuf;
      const float* S1p = Sbuf + 4096;
      const float* S0p = Sbuf + 8192;
      const float* pa = (kblk == 0) ? S2p : (kblk == 1) ? S1p : (kblk == 2) ? S0p : nullptr;
      const float* pb = (kblk == 1) ? S2p : (kblk == 2) ? S1p : (kblk == 3) ? S0p : nullptr;
      float acc = 0.0f;
#pragma unroll 4
      for (int k = 0; k < 64; ++k) {
        if (pa) acc += pa[t * 64 + k] * Wl3[j * 64 + k];
        if (pb) acc += pb[t * 64 + k] * Wr3[j * 64 + k];
      }
      Gbuf[idx] = acc;
    } else if (tid < 32) {
      float acc = bl3[tid];
      for (int k = 0; k < 64; ++k)
        acc += c5[k] * (Wl3[tid * 64 + k] + Wr3[tid * 64 + k]);
      c32[tid] = acc;
    }
  } else {
    // ---- sage1 GEMM ----
    constexpr int C = 128, K = 128, ROWS = 16, RPT = ROWS * C / 256;
    float* Xs = smem;
    int y0 = (u - 252) * ROWS;
    {
      const float4* src = (const float4*)(X + (size_t)y0 * K);
      float4* dst = (float4*)Xs;
#pragma unroll
      for (int v = 0; v < ROWS * K / 4 / 256; ++v)
        dst[v * 256 + tid] = src[v * 256 + tid];
    }
    __syncthreads();
    int uu = tid % C;
    int rg = tid / C;
    float acc[RPT];
#pragma unroll
    for (int k = 0; k < RPT; ++k) acc[k] = 0.0f;
#pragma unroll 2
    for (int w0 = 0; w0 < K; w0 += 4) {
      float m0 = Wt1[(w0 + 0) * C + uu];
      float m1 = Wt1[(w0 + 1) * C + uu];
      float m2 = Wt1[(w0 + 2) * C + uu];
      float m3 = Wt1[(w0 + 3) * C + uu];
      const float* xs = &Xs[(rg * RPT) * K + w0];
#pragma unroll
      for (int k = 0; k < RPT; ++k) {
        float4 h = *(const float4*)(xs + k * K);
        acc[k] += m0 * h.x + m1 * h.y + m2 * h.z + m3 * h.w;
      }
    }
#pragma unroll
    for (int k = 0; k < RPT; ++k)
      yzA[(size_t)(y0 + rg * RPT + k) * C + uu] = acc[k];
  }
}

// ---------- Phase 2 unit: partition(0..156) | setupWg(157..189) -------------
__device__ __forceinline__ void ph_two(
    int u, int tid, float* smem,
    const int* __restrict__ ei, const int* __restrict__ bins,
    int* __restrict__ bcur, unsigned long long* __restrict__ ebuf,
    const float* __restrict__ Gbuf, const float* __restrict__ W2,
    const float* __restrict__ b2, float* __restrict__ Wg,
    float* __restrict__ bg, int E) {
  if (u < 157) {
    int* lcnt  = (int*)smem;          // 79
    int* lbase = (int*)smem + 79;     // 79
    int* sscan = (int*)smem + 158;    // 128
    int st = probe_stride(ei);
    for (int i = tid; i < NBUK; i += 256) lcnt[i] = 0;
    int mine = 0;
    if (tid < 128) { mine = (tid < NBUK) ? bins[tid] : 0; sscan[tid] = mine; }
    __syncthreads();
    for (int off = 1; off < 128; off <<= 1) {
      int v = 0;
      if (tid < 128 && tid >= off) v = sscan[tid - off];
      __syncthreads();
      if (tid < 128) sscan[tid] += v;
      __syncthreads();
    }
    if (tid < 128) sscan[tid] -= mine;  // exclusive prefix = bucket base
    __syncthreads();
    int e0 = u * 4096;
    int srcv[16], dstv[16], lrank[16], bk[16];
    int n = 0;
#pragma unroll
    for (int t = 0; t < 16; ++t) {
      int e = e0 + t * 256 + tid;
      if (e < E) {
        int sv = ei[(size_t)e * st];
        int d = ei[(size_t)(E + e) * st];
        int bb = d >> 8;
        srcv[n] = sv; dstv[n] = d; bk[n] = bb;
        lrank[n] = atomicAdd(&lcnt[bb], 1);
        ++n;
      }
    }
    __syncthreads();
    for (int i = tid; i < NBUK; i += 256)
      lbase[i] = sscan[i] + atomicAdd(&bcur[i], lcnt[i]);
    __syncthreads();
    for (int t = 0; t < n; ++t) {
      int pos = lbase[bk[t]] + lrank[t];
      ebuf[pos] = ((unsigned long long)(unsigned)dstv[t] << 32) | (unsigned)srcv[t];
    }
  } else {
    int bb = u - 157;
    if (bb < 32) {
      int idx = bb * 256 + tid;  // Wg[w*128+u]
      int w = idx >> 7, uu = idx & 127;
      int kblk = uu >> 5, j = uu & 31;
      const float* gp = Gbuf + kblk * 2048 + j;
      float acc = 0.0f;
#pragma unroll 4
      for (int t = 0; t < 64; ++t) acc += W2[t * 64 + w] * gp[t * 32];
      Wg[idx] = acc;
    } else if (tid < 128) {
      int kblk = tid >> 5, j = tid & 31;
      const float* gp = Gbuf + kblk * 2048 + j;
      float acc = 0.0f;
      for (int t = 0; t < 64; ++t) acc += b2[t] * gp[t * 32];
      bg[tid] = acc;
    }
  }
}

// ---------- Phase 3 unit: per-bucket counting sort --------------------------
__device__ __forceinline__ void ph_sort(
    int b, int tid, float* smemf,
    const unsigned long long* __restrict__ ebuf, const int* __restrict__ bins,
    int* __restrict__ rowptr, float* __restrict__ invdeg,
    int* __restrict__ csr, int N) {
  int* smem = (int*)smemf;
  int* lcnt  = smem;
  int* lcur  = smem + 256;
  int* wsum  = smem + 512;
  int* sscan = smem + 516;
  int mine = 0;
  if (tid < 128) { mine = (tid < NBUK) ? bins[tid] : 0; sscan[tid] = mine; }
  __syncthreads();
  for (int off = 1; off < 128; off <<= 1) {
    int v = 0;
    if (tid < 128 && tid >= off) v = sscan[tid - off];
    __syncthreads();
    if (tid < 128) sscan[tid] += v;
    __syncthreads();
  }
  if (tid < 128) sscan[tid] -= mine;
  __syncthreads();
  int base = sscan[b];
  int n = bins[b];
  lcnt[tid] = 0;
  __syncthreads();
  for (int e = tid; e < n; e += 256) {
    int d = (int)(ebuf[base + e] >> 32);
    atomicAdd(&lcnt[d - (b << 8)], 1);
  }
  __syncthreads();
  int c = lcnt[tid];
  int lane = tid & 63, wid = tid >> 6;
  int s = c;
#pragma unroll
  for (int off = 1; off < 64; off <<= 1) {
    int v = __shfl_up(s, off, 64);
    if (lane >= off) s += v;
  }
  if (lane == 63) wsum[wid] = s;
  __syncthreads();
  int woff = 0;
  for (int w = 0; w < wid; ++w) woff += wsum[w];
  int pref = woff + s - c;  // exclusive
  int gnode = (b << 8) + tid;
  if (gnode < N) {
    rowptr[gnode] = base + pref;
    invdeg[gnode] = 1.0f / (float)(c < 1 ? 1 : c);
  }
  lcur[tid] = pref;
  __syncthreads();
  for (int e = tid; e < n; e += 256) {
    unsigned long long pk = ebuf[base + e];
    int d = (int)(pk >> 32);
    int pos = atomicAdd(&lcur[d - (b << 8)], 1);
    csr[base + pos] = (int)(unsigned)pk;
  }
}

// ---------- fused mean-aggregation + GEMM unit ------------------------------
template <int C>
__device__ __forceinline__ void ph_fused(
    int ublk, int tid, float* smem,
    const float* __restrict__ yzin, const int* __restrict__ csr,
    const int* __restrict__ rowptr, const float* __restrict__ invdeg,
    const float* __restrict__ bl, const float* __restrict__ Wt,
    float* __restrict__ out) {
  constexpr int FV = 16;
  constexpr int G  = 4;
  constexpr int S4 = 32;
  constexpr int CAP = 64;
  int* idxs = (int*)smem;          // 16*64 ints
  float* htile = smem + 1024;      // 16*64 floats
  int w = tid >> 6, lane = tid & 63;
  int base = ublk * 16;
  int beg_r[4], m_r[4], end_r[4];
#pragma unroll
  for (int rr = 0; rr < 4; ++rr) {
    int node = base + w * 4 + rr;
    int beg = rowptr[node], end = rowptr[node + 1];
    beg_r[rr] = beg; end_r[rr] = end;
    int cnt = end - beg;
    int m = cnt < CAP ? cnt : CAP;
    m_r[rr] = m;
    int* my = &idxs[(w * 4 + rr) * CAP];
    for (int k = lane; k < m; k += 64) my[k] = csr[beg + k];
  }
  __syncthreads();
  int g = lane / FV, f = lane % FV;
  const float4* yz4 = (const float4*)yzin;
#pragma unroll
  for (int rr = 0; rr < 4; ++rr) {
    int node = base + w * 4 + rr;
    const int* my = &idxs[(w * 4 + rr) * CAP];
    int m = m_r[rr];
    float a0x=0,a0y=0,a0z=0,a0w=0, a1x=0,a1y=0,a1z=0,a1w=0;
    float a2x=0,a2y=0,a2z=0,a2w=0, a3x=0,a3y=0,a3z=0,a3w=0;
    int j = g;
    for (; j + 3 * G < m; j += 4 * G) {
      int s0 = my[j], s1 = my[j + G], s2 = my[j + 2 * G], s3 = my[j + 3 * G];
      float4 v0 = yz4[(size_t)s0 * S4 + f];
      float4 v1 = yz4[(size_t)s1 * S4 + f];
      float4 v2 = yz4[(size_t)s2 * S4 + f];
      float4 v3 = yz4[(size_t)s3 * S4 + f];
      a0x += v0.x; a0y += v0.y; a0z += v0.z; a0w += v0.w;
      a1x += v1.x; a1y += v1.y; a1z += v1.z; a1w += v1.w;
      a2x += v2.x; a2y += v2.y; a2z += v2.z; a2w += v2.w;
      a3x += v3.x; a3y += v3.y; a3z += v3.z; a3w += v3.w;
    }
    for (; j < m; j += G) {
      int s0 = my[j];
      float4 v0 = yz4[(size_t)s0 * S4 + f];
      a0x += v0.x; a0y += v0.y; a0z += v0.z; a0w += v0.w;
    }
    for (int jj = beg_r[rr] + CAP + g; jj < end_r[rr]; jj += G) {
      int s0 = csr[jj];
      float4 v0 = yz4[(size_t)s0 * S4 + f];
      a0x += v0.x; a0y += v0.y; a0z += v0.z; a0w += v0.w;
    }
    float ax = (a0x + a1x) + (a2x + a3x);
    float ay = (a0y + a1y) + (a2y + a3y);
    float az = (a0z + a1z) + (a2z + a3z);
    float aw = (a0w + a1w) + (a2w + a3w);
#pragma unroll
    for (int mm = FV; mm < 64; mm <<= 1) {
      ax += __shfl_xor(ax, mm, 64);
      ay += __shfl_xor(ay, mm, 64);
      az += __shfl_xor(az, mm, 64);
      aw += __shfl_xor(aw, mm, 64);
    }
    if (g == 0) {
      float4 root = yz4[(size_t)node * S4 + FV + f];
      float4 bv = ((const float4*)bl)[f];
      float id = invdeg[node];
      float4 o;
      o.x = ax * id + bv.x + root.x;
      o.y = ay * id + bv.y + root.y;
      o.z = az * id + bv.z + root.z;
      o.w = aw * id + bv.w + root.w;
      ((float4*)htile)[(w * 4 + rr) * 16 + f] = o;
    }
  }
  __syncthreads();
  constexpr int RPT = 16 * C / 256;
  int u = tid % C, rg = tid / C;
  float acc[RPT];
#pragma unroll
  for (int k = 0; k < RPT; ++k) acc[k] = 0.0f;
#pragma unroll 2
  for (int w0 = 0; w0 < 64; w0 += 4) {
    float m0 = Wt[(w0 + 0) * C + u];
    float m1 = Wt[(w0 + 1) * C + u];
    float m2 = Wt[(w0 + 2) * C + u];
    float m3 = Wt[(w0 + 3) * C + u];
    const float* xs = &htile[(rg * RPT) * 64 + w0];
#pragma unroll
    for (int k = 0; k < RPT; ++k) {
      float4 h4 = *(const float4*)(xs + k * 64);
      acc[k] += m0 * h4.x + m1 * h4.y + m2 * h4.z + m3 * h4.w;
    }
  }
#pragma unroll
  for (int k = 0; k < RPT; ++k)
    out[(size_t)(base + rg * RPT + k) * C + u] = acc[k];
}

// ---------- standalone 64-wide mean aggregation unit ------------------------
__device__ __forceinline__ void ph_agg64(
    int ublk, int tid, float* smem,
    const float* __restrict__ yz, const int* __restrict__ csr,
    const int* __restrict__ rowptr, const float* __restrict__ invdeg,
    const float* __restrict__ bl, float* __restrict__ out) {
  constexpr int FV = 16;
  constexpr int G  = 4;
  constexpr int S4 = 32;
  constexpr int CAP = 256;
  int* idxs = (int*)smem;  // 4*256 ints
  int wid = tid >> 6, lane = tid & 63;
  int node = ublk * 4 + wid;
  int beg = rowptr[node], end = rowptr[node + 1];
  int cnt = end - beg;
  int m = cnt < CAP ? cnt : CAP;
  int* my = &idxs[wid * CAP];
  for (int k = lane; k < m; k += 64) my[k] = csr[beg + k];
  __syncthreads();
  int g = lane / FV, f = lane % FV;
  const float4* yz4 = (const float4*)yz;
  float a0x=0,a0y=0,a0z=0,a0w=0, a1x=0,a1y=0,a1z=0,a1w=0;
  float a2x=0,a2y=0,a2z=0,a2w=0, a3x=0,a3y=0,a3z=0,a3w=0;
  int j = g;
  for (; j + 3 * G < m; j += 4 * G) {
    int s0 = my[j], s1 = my[j + G], s2 = my[j + 2 * G], s3 = my[j + 3 * G];
    float4 v0 = yz4[(size_t)s0 * S4 + f];
    float4 v1 = yz4[(size_t)s1 * S4 + f];
    float4 v2 = yz4[(size_t)s2 * S4 + f];
    float4 v3 = yz4[(size_t)s3 * S4 + f];
    a0x += v0.x; a0y += v0.y; a0z += v0.z; a0w += v0.w;
    a1x += v1.x; a1y += v1.y; a1z += v1.z; a1w += v1.w;
    a2x += v2.x; a2y += v2.y; a2z += v2.z; a2w += v2.w;
    a3x += v3.x; a3y += v3.y; a3z += v3.z; a3w += v3.w;
  }
  for (; j < m; j += G) {
    int s0 = my[j];
    float4 v0 = yz4[(size_t)s0 * S4 + f];
    a0x += v0.x; a0y += v0.y; a0z += v0.z; a0w += v0.w;
  }
  for (int jj = beg + CAP + g; jj < end; jj += G) {
    int s0 = csr[jj];
    float4 v0 = yz4[(size_t)s0 * S4 + f];
    a0x += v0.x; a0y += v0.y; a0z += v0.z; a0w += v0.w;
  }
  float ax = (a0x + a1x) + (a2x + a3x);
  float ay = (a0y + a1y) + (a2y + a3y);
  float az = (a0z + a1z) + (a2z + a3z);
  float aw = (a0w + a1w) + (a2w + a3w);
#pragma unroll
  for (int mm = FV; mm < 64; mm <<= 1) {
    ax += __shfl_xor(ax, mm, 64);
    ay += __shfl_xor(ay, mm, 64);
    az += __shfl_xor(az, mm, 64);
    aw += __shfl_xor(aw, mm, 64);
  }
  if (g == 0) {
    float4 root = yz4[(size_t)node * S4 + FV + f];
    float4 bv = ((const float4*)bl)[f];
    float id = invdeg[node];
    float4 o;
    o.x = ax * id + bv.x + root.x;
    o.y = ay * id + bv.y + root.y;
    o.z = az * id + bv.z + root.z;
    o.w = aw * id + bv.w + root.w;
    ((float4*)out)[(size_t)node * FV + f] = o;
  }
}

// ---------- conv-composite apply + (linear2 ∘ sage4-6 collapse) unit --------
__device__ __forceinline__ void ph_apply(
    int ublk, int tid, float* smem,
    const float* __restrict__ h, const float* __restrict__ M5T,
    const float* __restrict__ beta5, const float* __restrict__ Wg,
    const float* __restrict__ bg, float* __restrict__ wout, int N) {
  float* hs = smem;            // 22*70
  float* htile = smem + 1540;  // 16*64
  int bstart = ublk * 16;
  for (int idx = tid; idx < 22 * 70; idx += 256) {
    int row = idx / 70, col = idx - row * 70;
    int y = bstart - 3 + row;
    int ww = col - 3;
    float v = 0.0f;
    if ((unsigned)y < (unsigned)N && (unsigned)ww < 64u)
      v = h[(size_t)y * 64 + ww];
    hs[idx] = v;
  }
  __syncthreads();
  int u = tid & 63, g = tid >> 6;
  int lr0 = g * 4;
  int gstart = bstart + lr0;
  const float* basep = &hs[lr0 * 70 + u];
  bool interior = (gstart >= 2) && (gstart + 3 <= N - 3);
  if (interior) {
    float bet = beta5[2 * 64 + u];
    float acc[4];
#pragma unroll
    for (int k = 0; k < 4; ++k) acc[k] = bet;
#pragma unroll
    for (int d = 0; d < 7; ++d) {
      float c7[7];
#pragma unroll
      for (int jw = 0; jw < 7; ++jw) c7[jw] = M5T[(2 * 49 + d * 7 + jw) * 64 + u];
#pragma unroll
      for (int k = 0; k < 4; ++k) {
        int rr = k + d;
        float s = 0.0f;
#pragma unroll
        for (int jw = 0; jw < 7; ++jw) s += c7[jw] * basep[rr * 70 + jw];
        acc[k] += s;
      }
    }
#pragma unroll
    for (int k = 0; k < 4; ++k) htile[(lr0 + k) * 64 + u] = acc[k];
  } else {
    for (int k = 0; k < 4; ++k) {
      int y = gstart + k;
      int var = (y == 0) ? 0 : (y == 1) ? 1 : (y == N - 2) ? 3 : (y == N - 1) ? 4 : 2;
      float acc = beta5[var * 64 + u];
      for (int d = 0; d < 7; ++d)
        for (int jw = 0; jw < 7; ++jw)
          acc += M5T[(var * 49 + d * 7 + jw) * 64 + u] * basep[(k + d) * 70 + jw];
      htile[(lr0 + k) * 64 + u] = acc;
    }
  }
  __syncthreads();
  int u2 = tid % 128, rg = tid / 128;
  float acc2[8];
  float bv = bg[u2];
#pragma unroll
  for (int k = 0; k < 8; ++k) acc2[k] = bv;
#pragma unroll 2
  for (int w0 = 0; w0 < 64; w0 += 4) {
    float m0 = Wg[(w0 + 0) * 128 + u2];
    float m1 = Wg[(w0 + 1) * 128 + u2];
    float m2 = Wg[(w0 + 2) * 128 + u2];
    float m3 = Wg[(w0 + 3) * 128 + u2];
    const float* xs = &htile[(rg * 8) * 64 + w0];
#pragma unroll
    for (int k = 0; k < 8; ++k) {
      float4 h4 = *(const float4*)(xs + k * 64);
      acc2[k] += m0 * h4.x + m1 * h4.y + m2 * h4.z + m3 * h4.w;
    }
  }
  int kb = u2 >> 5, jj = u2 & 31;
#pragma unroll
  for (int k = 0; k < 8; ++k) {
    int node = bstart + rg * 8 + k;
    wout[((size_t)kb * N + node) * 32 + jj] = acc2[k];
  }
}

// ---------- 32-wide mean aggregation + add unit -----------------------------
__device__ __forceinline__ void ph_agg32(
    int ublk, int tid, float* smem,
    const float* __restrict__ src, const int* __restrict__ csr,
    const int* __restrict__ rowptr, const float* __restrict__ invdeg,
    const float* __restrict__ add, const float* __restrict__ cvec,
    float* __restrict__ out) {
  constexpr int FV = 8;
  constexpr int G  = 8;
  constexpr int CAP = 256;
  int* idxs = (int*)smem;  // 4*256 ints
  int wid = tid >> 6, lane = tid & 63;
  int node = ublk * 4 + wid;
  int beg = rowptr[node], end = rowptr[node + 1];
  int cnt = end - beg;
  int m = cnt < CAP ? cnt : CAP;
  int* my = &idxs[wid * CAP];
  for (int k = lane; k < m; k += 64) my[k] = csr[beg + k];
  __syncthreads();
  int g = lane / FV, f = lane % FV;
  const float4* sr4 = (const float4*)src;
  float a0x=0,a0y=0,a0z=0,a0w=0, a1x=0,a1y=0,a1z=0,a1w=0;
  float a2x=0,a2y=0,a2z=0,a2w=0, a3x=0,a3y=0,a3z=0,a3w=0;
  int j = g;
  for (; j + 3 * G < m; j += 4 * G) {
    int s0 = my[j], s1 = my[j + G], s2 = my[j + 2 * G], s3 = my[j + 3 * G];
    float4 v0 = sr4[(size_t)s0 * FV + f];
    float4 v1 = sr4[(size_t)s1 * FV + f];
    float4 v2 = sr4[(size_t)s2 * FV + f];
    float4 v3 = sr4[(size_t)s3 * FV + f];
    a0x += v0.x; a0y += v0.y; a0z += v0.z; a0w += v0.w;
    a1x += v1.x; a1y += v1.y; a1z += v1.z; a1w += v1.w;
    a2x += v2.x; a2y += v2.y; a2z += v2.z; a2w += v2.w;
    a3x += v3.x; a3y += v3.y; a3z += v3.z; a3w += v3.w;
  }
  for (; j < m; j += G) {
    int s0 = my[j];
    float4 v0 = sr4[(size_t)s0 * FV + f];
    a0x += v0.x; a0y += v0.y; a0z += v0.z; a0w += v0.w;
  }
  for (int jj = beg + CAP + g; jj < end; jj += G) {
    int s0 = csr[jj];
    float4 v0 = sr4[(size_t)s0 * FV + f];
    a0x += v0.x; a0y += v0.y; a0z += v0.z; a0w += v0.w;
  }
  float ax = (a0x + a1x) + (a2x + a3x);
  float ay = (a0y + a1y) + (a2y + a3y);
  float az = (a0z + a1z) + (a2z + a3z);
  float aw = (a0w + a1w) + (a2w + a3w);
#pragma unroll
  for (int mm = FV; mm < 64; mm <<= 1) {
    ax += __shfl_xor(ax, mm, 64);
    ay += __shfl_xor(ay, mm, 64);
    az += __shfl_xor(az, mm, 64);
    aw += __shfl_xor(aw, mm, 64);
  }
  if (g == 0) {
    float4 av = ((const float4*)add)[(size_t)node * FV + f];
    float id = invdeg[node];
    float4 o;
    o.x = ax * id + av.x;
    o.y = ay * id + av.y;
    o.z = az * id + av.z;
    o.w = aw * id + av.w;
    if (cvec != nullptr) {
      float4 cv = ((const float4*)cvec)[f];
      o.x += cv.x; o.y += cv.y; o.z += cv.z; o.w += cv.w;
    }
    ((float4*)out)[(size_t)node * FV + f] = o;
  }
}

// ============================ MEGA KERNEL ====================================
// Normal launch; phases separated by manual device-scope barrier (gbar).
// Grid sized host-side from occupancy query -> all blocks co-resident.
__global__ __launch_bounds__(256, 4) void k_mega(MegaP p) {
  __shared__ float smem[6336];  // max branch: T729 setup (25.3 KB)
  int tid = threadIdx.x;
  const int GN = gridDim.x;

  // Ph0: weight setup + zero bins/bcur (152 units)
  for (int u = blockIdx.x; u < 152; u += GN) {
    ph_setup(u, tid, smem, p.Wc1, p.Wc2, p.Wc3, p.bc1, p.bc2, p.bc3,
             p.Wl1, p.Wr1, p.Wl2, p.Wr2, p.bl2,
             p.T729, p.beta5, p.Wt1, p.Wt2, p.Sbuf, p.c5,
             p.rowptr, p.bins, p.E, p.N);
    __syncthreads();
  }
  gbar(p.bar, 1);
  // Ph1: hist || M5T || G-matrices || sage1 GEMM (1502 units)
  for (int u = blockIdx.x; u < 1502; u += GN) {
    ph_one(u, tid, smem, p.x, p.Wt1, p.yzA, p.ei, p.bins,
           p.T729, p.M5T, p.Sbuf, p.c5, p.Wl3, p.Wr3, p.bl3,
           p.Gbuf, p.c32, p.E, p.N);
    __syncthreads();
  }
  gbar(p.bar, 2);
  // Ph2: partition || setupWg (190 units)
  for (int u = blockIdx.x; u < 190; u += GN) {
    ph_two(u, tid, smem, p.ei, p.bins, p.bcur, p.ebuf,
           p.Gbuf, p.W2, p.b2, p.Wg, p.bg, p.E);
    __syncthreads();
  }
  gbar(p.bar, 3);
  // Ph3: per-bucket counting sort (79 units)
  for (int u = blockIdx.x; u < NBUK; u += GN) {
    ph_sort(u, tid, smem, p.ebuf, p.bins, p.rowptr, p.invdeg, p.csr, p.N);
    __syncthreads();
  }
  gbar(p.bar, 4);
  // Ph4: agg1 + sage2-transform (1250 units)
  for (int u = blockIdx.x; u < 1250; u += GN) {
    ph_fused<128>(u, tid, smem, p.yzA, p.csr, p.rowptr, p.invdeg, p.bl1,
                  p.Wt2, p.yzB);
    __syncthreads();
  }
  gbar(p.bar, 5);
  // Ph5: agg2 + sage3-transform (1250 units)
  for (int u = blockIdx.x; u < 1250; u += GN) {
    ph_fused<128>(u, tid, smem, p.yzB, p.csr, p.rowptr, p.invdeg, p.bl2,
                  p.Wt2, p.yzA);
    __syncthreads();
  }
  gbar(p.bar, 6);
  // Ph6: agg3 -> hA (5000 units)
  for (int u = blockIdx.x; u < 5000; u += GN) {
    ph_agg64(u, tid, smem, p.yzA, p.csr, p.rowptr, p.invdeg, p.bl2, p.hA);
    __syncthreads();
  }
  gbar(p.bar, 7);
  // Ph7: conv composite + linear2 + collapse -> w3|w2|w1|w0 (1250 units)
  for (int u = blockIdx.x; u < 1250; u += GN) {
    ph_apply(u, tid, smem, p.hA, p.M5T, p.beta5, p.Wg, p.bg, p.wbuf, p.N);
    __syncthreads();
  }
  gbar(p.bar, 8);
  // Ph8-10: collapsed sage4-6 chain
  const float* w3  = p.wbuf;
  const float* w2p = p.wbuf + (size_t)p.N * 32;
  const float* w1p = p.wbuf + (size_t)2 * p.N * 32;
  const float* w0p = p.wbuf + (size_t)3 * p.N * 32;
  for (int u = blockIdx.x; u < 5000; u += GN) {
    ph_agg32(u, tid, smem, w3, p.csr, p.rowptr, p.invdeg, w2p, nullptr, p.s1);
    __syncthreads();
  }
  gbar(p.bar, 9);
  for (int u = blockIdx.x; u < 5000; u += GN) {
    ph_agg32(u, tid, smem, p.s1, p.csr, p.rowptr, p.invdeg, w1p, nullptr, p.s2);
    __syncthreads();
  }
  gbar(p.bar, 10);
  for (int u = blockIdx.x; u < 5000; u += GN) {
    ph_agg32(u, tid, smem, p.s2, p.csr, p.rowptr, p.invdeg, w0p, p.c32, p.dout);
    __syncthreads();
  }
}

// ------------------------------- launcher -----------------------------------
extern "C" void kernel_launch(void* const* d_in, const int* in_sizes, int n_in,
                              void* d_out, int out_size, void* d_ws, size_t ws_size,
                              hipStream_t stream) {
  const int N = NN, E = NE;
  char* ws = (char*)d_ws;
  size_t off = 0;
  auto alloc = [&](size_t bytes) -> void* {
    off = (off + 255) & ~(size_t)255;
    void* p = ws + off;
    off += bytes;
    return p;
  };
  int*   rowptr  = (int*)alloc((size_t)(N + 1) * 4);
  float* invdeg  = (float*)alloc((size_t)N * 4);
  int*   csr     = (int*)alloc((size_t)E * 4);
  unsigned long long* ebuf = (unsigned long long*)alloc((size_t)E * 8);
  int*   binsbuf = (int*)alloc(256 * 4);   // bins[128] | bcur[128]
  int*   barptr  = (int*)alloc(256);       // grid-barrier counter
  float* Wt1     = (float*)alloc(128 * 128 * 4);
  float* Wt2     = (float*)alloc(64 * 128 * 4);
  float* T729    = (float*)alloc(729 * 4);
  float* M5T     = (float*)alloc(15680 * 4);
  float* beta5   = (float*)alloc(320 * 4);
  float* Sbuf    = (float*)alloc(12288 * 4);
  float* c5      = (float*)alloc(64 * 4);
  float* Gbuf    = (float*)alloc(8192 * 4);
  float* Wg      = (float*)alloc(8192 * 4);
  float* bg      = (float*)alloc(128 * 4);
  float* c32     = (float*)alloc(32 * 4);
  float* yzA     = (float*)alloc((size_t)N * 128 * 4);
  float* yzB     = (float*)alloc((size_t)N * 128 * 4);
  float* hA      = (float*)alloc((size_t)N * 64 * 4);
  float* wbuf    = (float*)alloc((size_t)4 * N * 32 * 4);
  float* s1buf   = (float*)alloc((size_t)N * 32 * 4);
  float* s2buf   = (float*)alloc((size_t)N * 32 * 4);
  (void)ws_size; (void)in_sizes; (void)n_in; (void)out_size;

  MegaP p;
  p.x   = (const float*)d_in[0];
  p.ei  = (const int*)d_in[1];
  p.Wl1 = (const float*)d_in[2];
  p.bl1 = (const float*)d_in[3];
  p.Wr1 = (const float*)d_in[4];
  p.Wl2 = (const float*)d_in[5];
  p.bl2 = (const float*)d_in[6];
  p.Wr2 = (const float*)d_in[7];
  p.Wl3 = (const float*)d_in[8];
  p.bl3 = (const float*)d_in[9];
  p.Wr3 = (const float*)d_in[10];
  p.Wc1 = (const float*)d_in[11];
  p.bc1 = (const float*)d_in[12];
  p.Wc2 = (const float*)d_in[13];
  p.bc2 = (const float*)d_in[14];
  p.Wc3 = (const float*)d_in[15];
  p.bc3 = (const float*)d_in[16];
  p.W2  = (const float*)d_in[17];
  p.b2  = (const float*)d_in[18];
  p.rowptr = rowptr; p.invdeg = invdeg; p.csr = csr; p.ebuf = ebuf;
  p.bins = binsbuf; p.bcur = binsbuf + 128; p.bar = barptr;
  p.Wt1 = Wt1; p.Wt2 = Wt2; p.T729 = T729; p.M5T = M5T; p.beta5 = beta5;
  p.Sbuf = Sbuf; p.c5 = c5; p.Gbuf = Gbuf; p.Wg = Wg; p.bg = bg; p.c32 = c32;
  p.yzA = yzA; p.yzB = yzB; p.hA = hA; p.wbuf = wbuf; p.s1 = s1buf; p.s2 = s2buf;
  p.dout = (float*)d_out;
  p.E = E; p.N = N;

  // Grid sized to guaranteed co-residency (deadlock-free manual barrier):
  // query once; __launch_bounds__(256,4) caps VGPR<=128 (4 blocks/CU),
  // LDS 25.3KB allows 6/CU -> expect occ=4 -> grid=1024.
  static int s_grid = 0;
  if (s_grid == 0) {
    int occ = 0;
    hipError_t e = hipOccupancyMaxActiveBlocksPerMultiprocessor(&occ, k_mega,
                                                                256, 0);
    if (e != hipSuccess || occ < 1) occ = 3;  // conservative fallback
    long g = (long)occ * 256;                 // 256 CUs on MI355X
    if (g > 2048) g = 2048;
    s_grid = (int)g;
  }

  hipMemsetAsync(barptr, 0, 4, stream);  // barrier counter must start at 0
  hipLaunchKernelGGL(k_mega, dim3(s_grid), dim3(256), 0, stream, p);
}

// Round 7
// 880.272 us; speedup vs baseline: 2.2892x; 2.2892x over previous
//
#include <hip/hip_runtime.h>

#define NN 20000
#define NE 640000
#define NBUK 79  // ceil(20000/256) buckets of 256 nodes

// Self-probe: int64 edge data (values < 2^31) has every odd int32 word == 0.
__device__ __forceinline__ int probe_stride(const int* __restrict__ ei32) {
  int lane = threadIdx.x & 63;
  int v = ei32[2 * lane + 1];
  unsigned long long nz = __ballot(v != 0);
  return (nz == 0ull) ? 2 : 1;
}

__device__ __forceinline__ bool maskB(int var, int o2, int o1) {
  int s = o2 + o1;
  switch (var) {
    case 0: return (o2 >= 0) && (s >= 0);
    case 1: return s >= -1;
    case 3: return s <= 1;
    case 4: return (o2 <= 0) && (s <= 0);
    default: return true;
  }
}

// ---- manual grid barrier: monotone arrival counter, device-scope ----------
// R5 bug: ACQUIRE ordering inside the poll loop emitted buffer_inv (L1/L2
// invalidate) EVERY iteration -> 1024 spinners thrashed all caches ->
// FETCH 203MB, 79 GB/s, 2015us. Fix: RELAXED polls (plain coherent load,
// no invalidate), ONE release-RMW on arrive, ONE acquire fence on exit.
// (R6: __hip_atomic_fence doesn't exist; use __builtin_amdgcn_fence.)
__device__ __forceinline__ void gbar(int* bar, int gen) {
  __syncthreads();
  if (threadIdx.x == 0) {
    // arrive: release RMW (single buffer_wbl2 flushes this block's writes)
    __hip_atomic_fetch_add(bar, 1, __ATOMIC_RELEASE, __HIP_MEMORY_SCOPE_AGENT);
    int target = gen * (int)gridDim.x;
    while (__hip_atomic_load(bar, __ATOMIC_RELAXED, __HIP_MEMORY_SCOPE_AGENT) <
           target) {
      __builtin_amdgcn_s_sleep(8);  // ~512 cyc: throttle probe traffic
    }
    __builtin_amdgcn_fence(__ATOMIC_ACQUIRE, "agent");  // invalidate ONCE
  }
  __syncthreads();
}

struct MegaP {
  const float* x; const int* ei;
  const float* Wl1; const float* bl1; const float* Wr1;
  const float* Wl2; const float* bl2; const float* Wr2;
  const float* Wl3; const float* bl3; const float* Wr3;
  const float* Wc1; const float* bc1; const float* Wc2; const float* bc2;
  const float* Wc3; const float* bc3; const float* W2; const float* b2;
  int* rowptr; float* invdeg; int* csr; unsigned long long* ebuf;
  int* bins; int* bcur; int* bar;
  float* Wt1; float* Wt2; float* T729; float* M5T; float* beta5;
  float* Sbuf; float* c5; float* Gbuf; float* Wg; float* bg; float* c32;
  float* yzA; float* yzB; float* hA; float* wbuf; float* s1; float* s2;
  float* dout;
  int E; int N;
};

// ---------- Phase 0 unit: weight setup (0..150) + zero bins (151) -----------
__device__ __forceinline__ void ph_setup(
    int s, int tid, float* smem,
    const float* __restrict__ Wc1, const float* __restrict__ Wc2,
    const float* __restrict__ Wc3, const float* __restrict__ bc1,
    const float* __restrict__ bc2, const float* __restrict__ bc3,
    const float* __restrict__ Wl1, const float* __restrict__ Wr1,
    const float* __restrict__ Wl2, const float* __restrict__ Wr2,
    const float* __restrict__ bl2,
    float* __restrict__ T729, float* __restrict__ beta5,
    float* __restrict__ Wt1, float* __restrict__ Wt2,
    float* __restrict__ Sbuf, float* __restrict__ c5,
    int* __restrict__ rowptr, int* __restrict__ binsbuf, int E, int N) {
  if (s == 151) {
    binsbuf[tid] = 0;  // bins[128] | bcur[128]
  } else if (s == 0) {
    // ---- conv composite T729 ----
    float* W3  = smem;         // 576
    float* S9s = smem + 576;   // 5184
    float* W1s = smem + 5760;  // 576
    if (tid == 0) rowptr[N] = E;
    for (int e = tid; e < 576; e += 256) { W3[e] = Wc3[e]; W1s[e] = Wc1[e]; }
    __syncthreads();
    for (int bb = tid; bb < 576; bb += 256) {
      float acc[9];
#pragma unroll
      for (int a = 0; a < 9; ++a) acc[a] = 0.0f;
#pragma unroll 4
      for (int o = 0; o < 64; ++o) {
        float w2 = Wc2[o * 576 + bb];
#pragma unroll
        for (int a = 0; a < 9; ++a) acc[a] += W3[o * 9 + a] * w2;
      }
#pragma unroll
      for (int a = 0; a < 9; ++a) S9s[a * 576 + bb] = acc[a];
    }
    __syncthreads();
    for (int c = tid; c < 729; c += 256) {
      int kx0  = c % 3;
      int dl1e = (c / 3) % 3;
      int dl2e = (c / 9) % 3;
      int ky0  = (c / 27) % 3;
      int ky1  = (c / 81) % 3;
      int ky2  = c / 243;
      const float* s9 = &S9s[(ky2 * 3 + dl2e) * 576 + ky1 * 3 + dl1e];
      const float* w1 = &W1s[ky0 * 3 + kx0];
      float t = 0.0f;
#pragma unroll 8
      for (int i = 0; i < 64; ++i) t += s9[i * 9] * w1[i * 9];
      T729[c] = t;
    }
  } else if (s <= 5) {
    // ---- boundary beta vectors ----
    float* S2   = smem;          // 576
    float* W3b  = smem + 576;    // 576
    float* B2   = smem + 1152;   // 64
    float* part = smem + 1216;   // 256
    int var = s - 1;
    for (int e = tid; e < 576; e += 256) {
      int o = e / 9, r = e - o * 9;
      float t = 0.0f;
      for (int i = 0; i < 64; ++i) t += Wc2[o * 576 + i * 9 + r] * bc1[i];
      S2[e] = t;
      W3b[e] = Wc3[e];
    }
    if (tid < 64) B2[tid] = bc2[tid];
    __syncthreads();
    int u = tid & 63, oc = tid >> 6;
    float acc = 0.0f;
    for (int ky2 = 0; ky2 < 3; ++ky2) {
      int o2 = ky2 - 1;
      bool okA = (var == 0) ? (o2 >= 0) : (var == 4) ? (o2 <= 0) : true;
      if (!okA) continue;
      for (int dl2 = -1; dl2 <= 1; ++dl2) {
        int p = u + dl2; if ((unsigned)p >= 64u) continue;
        float sel[9];
#pragma unroll
        for (int ky1 = 0; ky1 < 3; ++ky1) {
          int o1 = ky1 - 1;
          bool mb = maskB(var, o2, o1);
#pragma unroll
          for (int dl1 = -1; dl1 <= 1; ++dl1) {
            int pq = p + dl1;
            sel[ky1 * 3 + dl1 + 1] = (mb && (unsigned)pq < 64u) ? 1.0f : 0.0f;
          }
        }
#pragma unroll 4
        for (int oo = 0; oo < 16; ++oo) {
          int o = oc * 16 + oo;
          float inner = B2[o];
#pragma unroll
          for (int r = 0; r < 9; ++r) inner += S2[o * 9 + r] * sel[r];
          acc += W3b[o * 9 + ky2 * 3 + (dl2 + 1)] * inner;
        }
      }
    }
    part[tid] = acc;
    __syncthreads();
    if (tid < 64) {
      beta5[var * 64 + tid] =
          bc3[0] + part[tid] + part[64 + tid] + part[128 + tid] + part[192 + tid];
    }
  } else {
    // ---- transposes + S-matrices + c5 ----
    int idx = (s - 6) * 256 + tid;  // 0..37119
    if (idx < 16384) {
      int w = idx >> 7, u = idx & 127;
      Wt1[idx] = (u < 64) ? Wl1[u * 128 + w] : Wr1[(u - 64) * 128 + w];
    } else if (idx < 24576) {
      int t = idx - 16384;
      int w = t >> 7, u = t & 127;
      Wt2[t] = (u < 64) ? Wl2[u * 64 + w] : Wr2[(u - 64) * 64 + w];
    } else if (idx < 36864) {
      // S2 = P·P, S1 = Q·P + P·Q, S0 = Q·Q  (P=Wl2^T, Q=Wr2^T)
      int t2 = idx - 24576;
      int m = t2 >> 12, e = t2 & 4095;
      int i = e >> 6, j = e & 63;
      float acc = 0.0f;
#pragma unroll 4
      for (int k = 0; k < 64; ++k) {
        float wlj = Wl2[j * 64 + k], wrj = Wr2[j * 64 + k];
        float wli = Wl2[k * 64 + i], wri = Wr2[k * 64 + i];
        if (m == 0) acc += wli * wlj;
        else if (m == 1) acc += wri * wlj + wli * wrj;
        else acc += wri * wrj;
      }
      Sbuf[t2] = acc;
    } else if (idx < 36928) {
      // c5 = bl2^T (P + Q + I)
      int j = idx - 36864;
      float acc = bl2[j];
      for (int i = 0; i < 64; ++i)
        acc += bl2[i] * (Wl2[j * 64 + i] + Wr2[j * 64 + i]);
      c5[j] = acc;
    }
  }
}

// ---------- Phase 1 unit: hist(0..156) | m5(157..218) | G(219..251) | gemm --
__device__ __forceinline__ void ph_one(
    int u, int tid, float* smem,
    const float* __restrict__ X, const float* __restrict__ Wt1,
    float* __restrict__ yzA,
    const int* __restrict__ ei, int* __restrict__ bins,
    const float* __restrict__ T729, float* __restrict__ M5T,
    const float* __restrict__ Sbuf, const float* __restrict__ c5,
    const float* __restrict__ Wl3, const float* __restrict__ Wr3,
    const float* __restrict__ bl3, float* __restrict__ Gbuf,
    float* __restrict__ c32, int E, int N) {
  if (u < 157) {
    // ---- histogram ----
    int* lb = (int*)smem;
    int st = probe_stride(ei);
    for (int i = tid; i < NBUK; i += 256) lb[i] = 0;
    __syncthreads();
    int e0 = u * 4096;
#pragma unroll
    for (int t = 0; t < 16; ++t) {
      int e = e0 + t * 256 + tid;
      if (e < E) atomicAdd(&lb[ei[(size_t)(E + e) * st] >> 8], 1);
    }
    __syncthreads();
    for (int i = tid; i < NBUK; i += 256)
      if (lb[i]) atomicAdd(&bins[i], lb[i]);
  } else if (u < 219) {
    // ---- M5T ----
    float* Ts = smem;  // 729
    for (int e = tid; e < 729; e += 256) Ts[e] = T729[e];
    __syncthreads();
    int idx = (u - 157) * 256 + tid;
    if (idx < 15680) {
      int jw = idx % 7;
      int uu = (idx / 7) % 64;
      int d  = (idx / 448) % 7;
      int var = idx / 3136;
      int w = uu + jw - 3;
      float acc = 0.0f;
      if (w >= 0 && w < 64) {
        for (int ky2 = 0; ky2 < 3; ++ky2) {
          int o2 = ky2 - 1;
          for (int ky1 = 0; ky1 < 3; ++ky1) {
            int o1 = ky1 - 1;
            if (!maskB(var, o2, o1)) continue;
            int o0 = (d - 3) - o2 - o1;
            if (o0 < -1 || o0 > 1) continue;
            int ky0 = o0 + 1;
            int cbase = ((ky2 * 3 + ky1) * 3 + ky0) * 27;
#pragma unroll
            for (int kx0 = 0; kx0 < 3; ++kx0) {
              int jq = jw - kx0;
              if ((unsigned)jq >= 5u) continue;
              int q = uu + jq - 2;
              if ((unsigned)q >= 64u) continue;
#pragma unroll
              for (int dl2e = 0; dl2e < 3; ++dl2e) {
                int pp = uu + dl2e - 1;
                if ((unsigned)pp >= 64u) continue;
                int dl1e = jq - dl2e;
                if ((unsigned)dl1e >= 3u) continue;
                acc += Ts[cbase + dl2e * 9 + dl1e * 3 + kx0];
              }
            }
          }
        }
      }
      if (d == 3 && jw == 3) acc += 1.0f;  // residual
      M5T[(var * 49 + d * 7 + jw) * 64 + uu] = acc;
    }
  } else if (u < 252) {
    // ---- G-matrices ----
    int bb = u - 219;
    if (bb < 32) {
      int idx = bb * 256 + tid;
      int kblk = idx >> 11;
      int rem = idx & 2047;
      int t = rem >> 5, j = rem & 31;
      const float* S2p = Sbuf;
      const float* S1p = Sbuf + 4096;
      const float* S0p = Sbuf + 8192;
      const float* pa = (kblk == 0) ? S2p : (kblk == 1) ? S1p : (kblk == 2) ? S0p : nullptr;
      const float* pb = (kblk == 1) ? S2p : (kblk == 2) ? S1p : (kblk == 3) ? S0p : nullptr;
      float acc = 0.0f;
#pragma unroll 4
      for (int k = 0; k < 64; ++k) {
        if (pa) acc += pa[t * 64 + k] * Wl3[j * 64 + k];
        if (pb) acc += pb[t * 64 + k] * Wr3[j * 64 + k];
      }
      Gbuf[idx] = acc;
    } else if (tid < 32) {
      float acc = bl3[tid];
      for (int k = 0; k < 64; ++k)
        acc += c5[k] * (Wl3[tid * 64 + k] + Wr3[tid * 64 + k]);
      c32[tid] = acc;
    }
  } else {
    // ---- sage1 GEMM ----
    constexpr int C = 128, K = 128, ROWS = 16, RPT = ROWS * C / 256;
    float* Xs = smem;
    int y0 = (u - 252) * ROWS;
    {
      const float4* src = (const float4*)(X + (size_t)y0 * K);
      float4* dst = (float4*)Xs;
#pragma unroll
      for (int v = 0; v < ROWS * K / 4 / 256; ++v)
        dst[v * 256 + tid] = src[v * 256 + tid];
    }
    __syncthreads();
    int uu = tid % C;
    int rg = tid / C;
    float acc[RPT];
#pragma unroll
    for (int k = 0; k < RPT; ++k) acc[k] = 0.0f;
#pragma unroll 2
    for (int w0 = 0; w0 < K; w0 += 4) {
      float m0 = Wt1[(w0 + 0) * C + uu];
      float m1 = Wt1[(w0 + 1) * C + uu];
      float m2 = Wt1[(w0 + 2) * C + uu];
      float m3 = Wt1[(w0 + 3) * C + uu];
      const float* xs = &Xs[(rg * RPT) * K + w0];
#pragma unroll
      for (int k = 0; k < RPT; ++k) {
        float4 h = *(const float4*)(xs + k * K);
        acc[k] += m0 * h.x + m1 * h.y + m2 * h.z + m3 * h.w;
      }
    }
#pragma unroll
    for (int k = 0; k < RPT; ++k)
      yzA[(size_t)(y0 + rg * RPT + k) * C + uu] = acc[k];
  }
}

// ---------- Phase 2 unit: partition(0..156) | setupWg(157..189) -------------
__device__ __forceinline__ void ph_two(
    int u, int tid, float* smem,
    const int* __restrict__ ei, const int* __restrict__ bins,
    int* __restrict__ bcur, unsigned long long* __restrict__ ebuf,
    const float* __restrict__ Gbuf, const float* __restrict__ W2,
    const float* __restrict__ b2, float* __restrict__ Wg,
    float* __restrict__ bg, int E) {
  if (u < 157) {
    int* lcnt  = (int*)smem;          // 79
    int* lbase = (int*)smem + 79;     // 79
    int* sscan = (int*)smem + 158;    // 128
    int st = probe_stride(ei);
    for (int i = tid; i < NBUK; i += 256) lcnt[i] = 0;
    int mine = 0;
    if (tid < 128) { mine = (tid < NBUK) ? bins[tid] : 0; sscan[tid] = mine; }
    __syncthreads();
    for (int off = 1; off < 128; off <<= 1) {
      int v = 0;
      if (tid < 128 && tid >= off) v = sscan[tid - off];
      __syncthreads();
      if (tid < 128) sscan[tid] += v;
      __syncthreads();
    }
    if (tid < 128) sscan[tid] -= mine;  // exclusive prefix = bucket base
    __syncthreads();
    int e0 = u * 4096;
    int srcv[16], dstv[16], lrank[16], bk[16];
    int n = 0;
#pragma unroll
    for (int t = 0; t < 16; ++t) {
      int e = e0 + t * 256 + tid;
      if (e < E) {
        int sv = ei[(size_t)e * st];
        int d = ei[(size_t)(E + e) * st];
        int bb = d >> 8;
        srcv[n] = sv; dstv[n] = d; bk[n] = bb;
        lrank[n] = atomicAdd(&lcnt[bb], 1);
        ++n;
      }
    }
    __syncthreads();
    for (int i = tid; i < NBUK; i += 256)
      lbase[i] = sscan[i] + atomicAdd(&bcur[i], lcnt[i]);
    __syncthreads();
    for (int t = 0; t < n; ++t) {
      int pos = lbase[bk[t]] + lrank[t];
      ebuf[pos] = ((unsigned long long)(unsigned)dstv[t] << 32) | (unsigned)srcv[t];
    }
  } else {
    int bb = u - 157;
    if (bb < 32) {
      int idx = bb * 256 + tid;  // Wg[w*128+u]
      int w = idx >> 7, uu = idx & 127;
      int kblk = uu >> 5, j = uu & 31;
      const float* gp = Gbuf + kblk * 2048 + j;
      float acc = 0.0f;
#pragma unroll 4
      for (int t = 0; t < 64; ++t) acc += W2[t * 64 + w] * gp[t * 32];
      Wg[idx] = acc;
    } else if (tid < 128) {
      int kblk = tid >> 5, j = tid & 31;
      const float* gp = Gbuf + kblk * 2048 + j;
      float acc = 0.0f;
      for (int t = 0; t < 64; ++t) acc += b2[t] * gp[t * 32];
      bg[tid] = acc;
    }
  }
}

// ---------- Phase 3 unit: per-bucket counting sort --------------------------
__device__ __forceinline__ void ph_sort(
    int b, int tid, float* smemf,
    const unsigned long long* __restrict__ ebuf, const int* __restrict__ bins,
    int* __restrict__ rowptr, float* __restrict__ invdeg,
    int* __restrict__ csr, int N) {
  int* smem = (int*)smemf;
  int* lcnt  = smem;
  int* lcur  = smem + 256;
  int* wsum  = smem + 512;
  int* sscan = smem + 516;
  int mine = 0;
  if (tid < 128) { mine = (tid < NBUK) ? bins[tid] : 0; sscan[tid] = mine; }
  __syncthreads();
  for (int off = 1; off < 128; off <<= 1) {
    int v = 0;
    if (tid < 128 && tid >= off) v = sscan[tid - off];
    __syncthreads();
    if (tid < 128) sscan[tid] += v;
    __syncthreads();
  }
  if (tid < 128) sscan[tid] -= mine;
  __syncthreads();
  int base = sscan[b];
  int n = bins[b];
  lcnt[tid] = 0;
  __syncthreads();
  for (int e = tid; e < n; e += 256) {
    int d = (int)(ebuf[base + e] >> 32);
    atomicAdd(&lcnt[d - (b << 8)], 1);
  }
  __syncthreads();
  int c = lcnt[tid];
  int lane = tid & 63, wid = tid >> 6;
  int s = c;
#pragma unroll
  for (int off = 1; off < 64; off <<= 1) {
    int v = __shfl_up(s, off, 64);
    if (lane >= off) s += v;
  }
  if (lane == 63) wsum[wid] = s;
  __syncthreads();
  int woff = 0;
  for (int w = 0; w < wid; ++w) woff += wsum[w];
  int pref = woff + s - c;  // exclusive
  int gnode = (b << 8) + tid;
  if (gnode < N) {
    rowptr[gnode] = base + pref;
    invdeg[gnode] = 1.0f / (float)(c < 1 ? 1 : c);
  }
  lcur[tid] = pref;
  __syncthreads();
  for (int e = tid; e < n; e += 256) {
    unsigned long long pk = ebuf[base + e];
    int d = (int)(pk >> 32);
    int pos = atomicAdd(&lcur[d - (b << 8)], 1);
    csr[base + pos] = (int)(unsigned)pk;
  }
}

// ---------- fused mean-aggregation + GEMM unit ------------------------------
template <int C>
__device__ __forceinline__ void ph_fused(
    int ublk, int tid, float* smem,
    const float* __restrict__ yzin, const int* __restrict__ csr,
    const int* __restrict__ rowptr, const float* __restrict__ invdeg,
    const float* __restrict__ bl, const float* __restrict__ Wt,
    float* __restrict__ out) {
  constexpr int FV = 16;
  constexpr int G  = 4;
  constexpr int S4 = 32;
  constexpr int CAP = 64;
  int* idxs = (int*)smem;          // 16*64 ints
  float* htile = smem + 1024;      // 16*64 floats
  int w = tid >> 6, lane = tid & 63;
  int base = ublk * 16;
  int beg_r[4], m_r[4], end_r[4];
#pragma unroll
  for (int rr = 0; rr < 4; ++rr) {
    int node = base + w * 4 + rr;
    int beg = rowptr[node], end = rowptr[node + 1];
    beg_r[rr] = beg; end_r[rr] = end;
    int cnt = end - beg;
    int m = cnt < CAP ? cnt : CAP;
    m_r[rr] = m;
    int* my = &idxs[(w * 4 + rr) * CAP];
    for (int k = lane; k < m; k += 64) my[k] = csr[beg + k];
  }
  __syncthreads();
  int g = lane / FV, f = lane % FV;
  const float4* yz4 = (const float4*)yzin;
#pragma unroll
  for (int rr = 0; rr < 4; ++rr) {
    int node = base + w * 4 + rr;
    const int* my = &idxs[(w * 4 + rr) * CAP];
    int m = m_r[rr];
    float a0x=0,a0y=0,a0z=0,a0w=0, a1x=0,a1y=0,a1z=0,a1w=0;
    float a2x=0,a2y=0,a2z=0,a2w=0, a3x=0,a3y=0,a3z=0,a3w=0;
    int j = g;
    for (; j + 3 * G < m; j += 4 * G) {
      int s0 = my[j], s1 = my[j + G], s2 = my[j + 2 * G], s3 = my[j + 3 * G];
      float4 v0 = yz4[(size_t)s0 * S4 + f];
      float4 v1 = yz4[(size_t)s1 * S4 + f];
      float4 v2 = yz4[(size_t)s2 * S4 + f];
      float4 v3 = yz4[(size_t)s3 * S4 + f];
      a0x += v0.x; a0y += v0.y; a0z += v0.z; a0w += v0.w;
      a1x += v1.x; a1y += v1.y; a1z += v1.z; a1w += v1.w;
      a2x += v2.x; a2y += v2.y; a2z += v2.z; a2w += v2.w;
      a3x += v3.x; a3y += v3.y; a3z += v3.z; a3w += v3.w;
    }
    for (; j < m; j += G) {
      int s0 = my[j];
      float4 v0 = yz4[(size_t)s0 * S4 + f];
      a0x += v0.x; a0y += v0.y; a0z += v0.z; a0w += v0.w;
    }
    for (int jj = beg_r[rr] + CAP + g; jj < end_r[rr]; jj += G) {
      int s0 = csr[jj];
      float4 v0 = yz4[(size_t)s0 * S4 + f];
      a0x += v0.x; a0y += v0.y; a0z += v0.z; a0w += v0.w;
    }
    float ax = (a0x + a1x) + (a2x + a3x);
    float ay = (a0y + a1y) + (a2y + a3y);
    float az = (a0z + a1z) + (a2z + a3z);
    float aw = (a0w + a1w) + (a2w + a3w);
#pragma unroll
    for (int mm = FV; mm < 64; mm <<= 1) {
      ax += __shfl_xor(ax, mm, 64);
      ay += __shfl_xor(ay, mm, 64);
      az += __shfl_xor(az, mm, 64);
      aw += __shfl_xor(aw, mm, 64);
    }
    if (g == 0) {
      float4 root = yz4[(size_t)node * S4 + FV + f];
      float4 bv = ((const float4*)bl)[f];
      float id = invdeg[node];
      float4 o;
      o.x = ax * id + bv.x + root.x;
      o.y = ay * id + bv.y + root.y;
      o.z = az * id + bv.z + root.z;
      o.w = aw * id + bv.w + root.w;
      ((float4*)htile)[(w * 4 + rr) * 16 + f] = o;
    }
  }
  __syncthreads();
  constexpr int RPT = 16 * C / 256;
  int u = tid % C, rg = tid / C;
  float acc[RPT];
#pragma unroll
  for (int k = 0; k < RPT; ++k) acc[k] = 0.0f;
#pragma unroll 2
  for (int w0 = 0; w0 < 64; w0 += 4) {
    float m0 = Wt[(w0 + 0) * C + u];
    float m1 = Wt[(w0 + 1) * C + u];
    float m2 = Wt[(w0 + 2) * C + u];
    float m3 = Wt[(w0 + 3) * C + u];
    const float* xs = &htile[(rg * RPT) * 64 + w0];
#pragma unroll
    for (int k = 0; k < RPT; ++k) {
      float4 h4 = *(const float4*)(xs + k * 64);
      acc[k] += m0 * h4.x + m1 * h4.y + m2 * h4.z + m3 * h4.w;
    }
  }
#pragma unroll
  for (int k = 0; k < RPT; ++k)
    out[(size_t)(base + rg * RPT + k) * C + u] = acc[k];
}

// ---------- standalone 64-wide mean aggregation unit ------------------------
__device__ __forceinline__ void ph_agg64(
    int ublk, int tid, float* smem,
    const float* __restrict__ yz, const int* __restrict__ csr,
    const int* __restrict__ rowptr, const float* __restrict__ invdeg,
    const float* __restrict__ bl, float* __restrict__ out) {
  constexpr int FV = 16;
  constexpr int G  = 4;
  constexpr int S4 = 32;
  constexpr int CAP = 256;
  int* idxs = (int*)smem;  // 4*256 ints
  int wid = tid >> 6, lane = tid & 63;
  int node = ublk * 4 + wid;
  int beg = rowptr[node], end = rowptr[node + 1];
  int cnt = end - beg;
  int m = cnt < CAP ? cnt : CAP;
  int* my = &idxs[wid * CAP];
  for (int k = lane; k < m; k += 64) my[k] = csr[beg + k];
  __syncthreads();
  int g = lane / FV, f = lane % FV;
  const float4* yz4 = (const float4*)yz;
  float a0x=0,a0y=0,a0z=0,a0w=0, a1x=0,a1y=0,a1z=0,a1w=0;
  float a2x=0,a2y=0,a2z=0,a2w=0, a3x=0,a3y=0,a3z=0,a3w=0;
  int j = g;
  for (; j + 3 * G < m; j += 4 * G) {
    int s0 = my[j], s1 = my[j + G], s2 = my[j + 2 * G], s3 = my[j + 3 * G];
    float4 v0 = yz4[(size_t)s0 * S4 + f];
    float4 v1 = yz4[(size_t)s1 * S4 + f];
    float4 v2 = yz4[(size_t)s2 * S4 + f];
    float4 v3 = yz4[(size_t)s3 * S4 + f];
    a0x += v0.x; a0y += v0.y; a0z += v0.z; a0w += v0.w;
    a1x += v1.x; a1y += v1.y; a1z += v1.z; a1w += v1.w;
    a2x += v2.x; a2y += v2.y; a2z += v2.z; a2w += v2.w;
    a3x += v3.x; a3y += v3.y; a3z += v3.z; a3w += v3.w;
  }
  for (; j < m; j += G) {
    int s0 = my[j];
    float4 v0 = yz4[(size_t)s0 * S4 + f];
    a0x += v0.x; a0y += v0.y; a0z += v0.z; a0w += v0.w;
  }
  for (int jj = beg + CAP + g; jj < end; jj += G) {
    int s0 = csr[jj];
    float4 v0 = yz4[(size_t)s0 * S4 + f];
    a0x += v0.x; a0y += v0.y; a0z += v0.z; a0w += v0.w;
  }
  float ax = (a0x + a1x) + (a2x + a3x);
  float ay = (a0y + a1y) + (a2y + a3y);
  float az = (a0z + a1z) + (a2z + a3z);
  float aw = (a0w + a1w) + (a2w + a3w);
#pragma unroll
  for (int mm = FV; mm < 64; mm <<= 1) {
    ax += __shfl_xor(ax, mm, 64);
    ay += __shfl_xor(ay, mm, 64);
    az += __shfl_xor(az, mm, 64);
    aw += __shfl_xor(aw, mm, 64);
  }
  if (g == 0) {
    float4 root = yz4[(size_t)node * S4 + FV + f];
    float4 bv = ((const float4*)bl)[f];
    float id = invdeg[node];
    float4 o;
    o.x = ax * id + bv.x + root.x;
    o.y = ay * id + bv.y + root.y;
    o.z = az * id + bv.z + root.z;
    o.w = aw * id + bv.w + root.w;
    ((float4*)out)[(size_t)node * FV + f] = o;
  }
}

// ---------- conv-composite apply + (linear2 ∘ sage4-6 collapse) unit --------
__device__ __forceinline__ void ph_apply(
    int ublk, int tid, float* smem,
    const float* __restrict__ h, const float* __restrict__ M5T,
    const float* __restrict__ beta5, const float* __restrict__ Wg,
    const float* __restrict__ bg, float* __restrict__ wout, int N) {
  float* hs = smem;            // 22*70
  float* htile = smem + 1540;  // 16*64
  int bstart = ublk * 16;
  for (int idx = tid; idx < 22 * 70; idx += 256) {
    int row = idx / 70, col = idx - row * 70;
    int y = bstart - 3 + row;
    int ww = col - 3;
    float v = 0.0f;
    if ((unsigned)y < (unsigned)N && (unsigned)ww < 64u)
      v = h[(size_t)y * 64 + ww];
    hs[idx] = v;
  }
  __syncthreads();
  int u = tid & 63, g = tid >> 6;
  int lr0 = g * 4;
  int gstart = bstart + lr0;
  const float* basep = &hs[lr0 * 70 + u];
  bool interior = (gstart >= 2) && (gstart + 3 <= N - 3);
  if (interior) {
    float bet = beta5[2 * 64 + u];
    float acc[4];
#pragma unroll
    for (int k = 0; k < 4; ++k) acc[k] = bet;
#pragma unroll
    for (int d = 0; d < 7; ++d) {
      float c7[7];
#pragma unroll
      for (int jw = 0; jw < 7; ++jw) c7[jw] = M5T[(2 * 49 + d * 7 + jw) * 64 + u];
#pragma unroll
      for (int k = 0; k < 4; ++k) {
        int rr = k + d;
        float s = 0.0f;
#pragma unroll
        for (int jw = 0; jw < 7; ++jw) s += c7[jw] * basep[rr * 70 + jw];
        acc[k] += s;
      }
    }
#pragma unroll
    for (int k = 0; k < 4; ++k) htile[(lr0 + k) * 64 + u] = acc[k];
  } else {
    for (int k = 0; k < 4; ++k) {
      int y = gstart + k;
      int var = (y == 0) ? 0 : (y == 1) ? 1 : (y == N - 2) ? 3 : (y == N - 1) ? 4 : 2;
      float acc = beta5[var * 64 + u];
      for (int d = 0; d < 7; ++d)
        for (int jw = 0; jw < 7; ++jw)
          acc += M5T[(var * 49 + d * 7 + jw) * 64 + u] * basep[(k + d) * 70 + jw];
      htile[(lr0 + k) * 64 + u] = acc;
    }
  }
  __syncthreads();
  int u2 = tid % 128, rg = tid / 128;
  float acc2[8];
  float bv = bg[u2];
#pragma unroll
  for (int k = 0; k < 8; ++k) acc2[k] = bv;
#pragma unroll 2
  for (int w0 = 0; w0 < 64; w0 += 4) {
    float m0 = Wg[(w0 + 0) * 128 + u2];
    float m1 = Wg[(w0 + 1) * 128 + u2];
    float m2 = Wg[(w0 + 2) * 128 + u2];
    float m3 = Wg[(w0 + 3) * 128 + u2];
    const float* xs = &htile[(rg * 8) * 64 + w0];
#pragma unroll
    for (int k = 0; k < 8; ++k) {
      float4 h4 = *(const float4*)(xs + k * 64);
      acc2[k] += m0 * h4.x + m1 * h4.y + m2 * h4.z + m3 * h4.w;
    }
  }
  int kb = u2 >> 5, jj = u2 & 31;
#pragma unroll
  for (int k = 0; k < 8; ++k) {
    int node = bstart + rg * 8 + k;
    wout[((size_t)kb * N + node) * 32 + jj] = acc2[k];
  }
}

// ---------- 32-wide mean aggregation + add unit -----------------------------
__device__ __forceinline__ void ph_agg32(
    int ublk, int tid, float* smem,
    const float* __restrict__ src, const int* __restrict__ csr,
    const int* __restrict__ rowptr, const float* __restrict__ invdeg,
    const float* __restrict__ add, const float* __restrict__ cvec,
    float* __restrict__ out) {
  constexpr int FV = 8;
  constexpr int G  = 8;
  constexpr int CAP = 256;
  int* idxs = (int*)smem;  // 4*256 ints
  int wid = tid >> 6, lane = tid & 63;
  int node = ublk * 4 + wid;
  int beg = rowptr[node], end = rowptr[node + 1];
  int cnt = end - beg;
  int m = cnt < CAP ? cnt : CAP;
  int* my = &idxs[wid * CAP];
  for (int k = lane; k < m; k += 64) my[k] = csr[beg + k];
  __syncthreads();
  int g = lane / FV, f = lane % FV;
  const float4* sr4 = (const float4*)src;
  float a0x=0,a0y=0,a0z=0,a0w=0, a1x=0,a1y=0,a1z=0,a1w=0;
  float a2x=0,a2y=0,a2z=0,a2w=0, a3x=0,a3y=0,a3z=0,a3w=0;
  int j = g;
  for (; j + 3 * G < m; j += 4 * G) {
    int s0 = my[j], s1 = my[j + G], s2 = my[j + 2 * G], s3 = my[j + 3 * G];
    float4 v0 = sr4[(size_t)s0 * FV + f];
    float4 v1 = sr4[(size_t)s1 * FV + f];
    float4 v2 = sr4[(size_t)s2 * FV + f];
    float4 v3 = sr4[(size_t)s3 * FV + f];
    a0x += v0.x; a0y += v0.y; a0z += v0.z; a0w += v0.w;
    a1x += v1.x; a1y += v1.y; a1z += v1.z; a1w += v1.w;
    a2x += v2.x; a2y += v2.y; a2z += v2.z; a2w += v2.w;
    a3x += v3.x; a3y += v3.y; a3z += v3.z; a3w += v3.w;
  }
  for (; j < m; j += G) {
    int s0 = my[j];
    float4 v0 = sr4[(size_t)s0 * FV + f];
    a0x += v0.x; a0y += v0.y; a0z += v0.z; a0w += v0.w;
  }
  for (int jj = beg + CAP + g; jj < end; jj += G) {
    int s0 = csr[jj];
    float4 v0 = sr4[(size_t)s0 * FV + f];
    a0x += v0.x; a0y += v0.y; a0z += v0.z; a0w += v0.w;
  }
  float ax = (a0x + a1x) + (a2x + a3x);
  float ay = (a0y + a1y) + (a2y + a3y);
  float az = (a0z + a1z) + (a2z + a3z);
  float aw = (a0w + a1w) + (a2w + a3w);
#pragma unroll
  for (int mm = FV; mm < 64; mm <<= 1) {
    ax += __shfl_xor(ax, mm, 64);
    ay += __shfl_xor(ay, mm, 64);
    az += __shfl_xor(az, mm, 64);
    aw += __shfl_xor(aw, mm, 64);
  }
  if (g == 0) {
    float4 av = ((const float4*)add)[(size_t)node * FV + f];
    float id = invdeg[node];
    float4 o;
    o.x = ax * id + av.x;
    o.y = ay * id + av.y;
    o.z = az * id + av.z;
    o.w = aw * id + av.w;
    if (cvec != nullptr) {
      float4 cv = ((const float4*)cvec)[f];
      o.x += cv.x; o.y += cv.y; o.z += cv.z; o.w += cv.w;
    }
    ((float4*)out)[(size_t)node * FV + f] = o;
  }
}

// ============================ MEGA KERNEL ====================================
// Normal launch; phases separated by manual device-scope barrier (gbar).
// Grid sized host-side from occupancy query -> all blocks co-resident.
__global__ __launch_bounds__(256, 4) void k_mega(MegaP p) {
  __shared__ float smem[6336];  // max branch: T729 setup (25.3 KB)
  int tid = threadIdx.x;
  const int GN = gridDim.x;

  // Ph0: weight setup + zero bins/bcur (152 units)
  for (int u = blockIdx.x; u < 152; u += GN) {
    ph_setup(u, tid, smem, p.Wc1, p.Wc2, p.Wc3, p.bc1, p.bc2, p.bc3,
             p.Wl1, p.Wr1, p.Wl2, p.Wr2, p.bl2,
             p.T729, p.beta5, p.Wt1, p.Wt2, p.Sbuf, p.c5,
             p.rowptr, p.bins, p.E, p.N);
    __syncthreads();
  }
  gbar(p.bar, 1);
  // Ph1: hist || M5T || G-matrices || sage1 GEMM (1502 units)
  for (int u = blockIdx.x; u < 1502; u += GN) {
    ph_one(u, tid, smem, p.x, p.Wt1, p.yzA, p.ei, p.bins,
           p.T729, p.M5T, p.Sbuf, p.c5, p.Wl3, p.Wr3, p.bl3,
           p.Gbuf, p.c32, p.E, p.N);
    __syncthreads();
  }
  gbar(p.bar, 2);
  // Ph2: partition || setupWg (190 units)
  for (int u = blockIdx.x; u < 190; u += GN) {
    ph_two(u, tid, smem, p.ei, p.bins, p.bcur, p.ebuf,
           p.Gbuf, p.W2, p.b2, p.Wg, p.bg, p.E);
    __syncthreads();
  }
  gbar(p.bar, 3);
  // Ph3: per-bucket counting sort (79 units)
  for (int u = blockIdx.x; u < NBUK; u += GN) {
    ph_sort(u, tid, smem, p.ebuf, p.bins, p.rowptr, p.invdeg, p.csr, p.N);
    __syncthreads();
  }
  gbar(p.bar, 4);
  // Ph4: agg1 + sage2-transform (1250 units)
  for (int u = blockIdx.x; u < 1250; u += GN) {
    ph_fused<128>(u, tid, smem, p.yzA, p.csr, p.rowptr, p.invdeg, p.bl1,
                  p.Wt2, p.yzB);
    __syncthreads();
  }
  gbar(p.bar, 5);
  // Ph5: agg2 + sage3-transform (1250 units)
  for (int u = blockIdx.x; u < 1250; u += GN) {
    ph_fused<128>(u, tid, smem, p.yzB, p.csr, p.rowptr, p.invdeg, p.bl2,
                  p.Wt2, p.yzA);
    __syncthreads();
  }
  gbar(p.bar, 6);
  // Ph6: agg3 -> hA (5000 units)
  for (int u = blockIdx.x; u < 5000; u += GN) {
    ph_agg64(u, tid, smem, p.yzA, p.csr, p.rowptr, p.invdeg, p.bl2, p.hA);
    __syncthreads();
  }
  gbar(p.bar, 7);
  // Ph7: conv composite + linear2 + collapse -> w3|w2|w1|w0 (1250 units)
  for (int u = blockIdx.x; u < 1250; u += GN) {
    ph_apply(u, tid, smem, p.hA, p.M5T, p.beta5, p.Wg, p.bg, p.wbuf, p.N);
    __syncthreads();
  }
  gbar(p.bar, 8);
  // Ph8-10: collapsed sage4-6 chain
  const float* w3  = p.wbuf;
  const float* w2p = p.wbuf + (size_t)p.N * 32;
  const float* w1p = p.wbuf + (size_t)2 * p.N * 32;
  const float* w0p = p.wbuf + (size_t)3 * p.N * 32;
  for (int u = blockIdx.x; u < 5000; u += GN) {
    ph_agg32(u, tid, smem, w3, p.csr, p.rowptr, p.invdeg, w2p, nullptr, p.s1);
    __syncthreads();
  }
  gbar(p.bar, 9);
  for (int u = blockIdx.x; u < 5000; u += GN) {
    ph_agg32(u, tid, smem, p.s1, p.csr, p.rowptr, p.invdeg, w1p, nullptr, p.s2);
    __syncthreads();
  }
  gbar(p.bar, 10);
  for (int u = blockIdx.x; u < 5000; u += GN) {
    ph_agg32(u, tid, smem, p.s2, p.csr, p.rowptr, p.invdeg, w0p, p.c32, p.dout);
    __syncthreads();
  }
}

// ------------------------------- launcher -----------------------------------
extern "C" void kernel_launch(void* const* d_in, const int* in_sizes, int n_in,
                              void* d_out, int out_size, void* d_ws, size_t ws_size,
                              hipStream_t stream) {
  const int N = NN, E = NE;
  char* ws = (char*)d_ws;
  size_t off = 0;
  auto alloc = [&](size_t bytes) -> void* {
    off = (off + 255) & ~(size_t)255;
    void* p = ws + off;
    off += bytes;
    return p;
  };
  int*   rowptr  = (int*)alloc((size_t)(N + 1) * 4);
  float* invdeg  = (float*)alloc((size_t)N * 4);
  int*   csr     = (int*)alloc((size_t)E * 4);
  unsigned long long* ebuf = (unsigned long long*)alloc((size_t)E * 8);
  int*   binsbuf = (int*)alloc(256 * 4);   // bins[128] | bcur[128]
  int*   barptr  = (int*)alloc(256);       // grid-barrier counter
  float* Wt1     = (float*)alloc(128 * 128 * 4);
  float* Wt2     = (float*)alloc(64 * 128 * 4);
  float* T729    = (float*)alloc(729 * 4);
  float* M5T     = (float*)alloc(15680 * 4);
  float* beta5   = (float*)alloc(320 * 4);
  float* Sbuf    = (float*)alloc(12288 * 4);
  float* c5      = (float*)alloc(64 * 4);
  float* Gbuf    = (float*)alloc(8192 * 4);
  float* Wg      = (float*)alloc(8192 * 4);
  float* bg      = (float*)alloc(128 * 4);
  float* c32     = (float*)alloc(32 * 4);
  float* yzA     = (float*)alloc((size_t)N * 128 * 4);
  float* yzB     = (float*)alloc((size_t)N * 128 * 4);
  float* hA      = (float*)alloc((size_t)N * 64 * 4);
  float* wbuf    = (float*)alloc((size_t)4 * N * 32 * 4);
  float* s1buf   = (float*)alloc((size_t)N * 32 * 4);
  float* s2buf   = (float*)alloc((size_t)N * 32 * 4);
  (void)ws_size; (void)in_sizes; (void)n_in; (void)out_size;

  MegaP p;
  p.x   = (const float*)d_in[0];
  p.ei  = (const int*)d_in[1];
  p.Wl1 = (const float*)d_in[2];
  p.bl1 = (const float*)d_in[3];
  p.Wr1 = (const float*)d_in[4];
  p.Wl2 = (const float*)d_in[5];
  p.bl2 = (const float*)d_in[6];
  p.Wr2 = (const float*)d_in[7];
  p.Wl3 = (const float*)d_in[8];
  p.bl3 = (const float*)d_in[9];
  p.Wr3 = (const float*)d_in[10];
  p.Wc1 = (const float*)d_in[11];
  p.bc1 = (const float*)d_in[12];
  p.Wc2 = (const float*)d_in[13];
  p.bc2 = (const float*)d_in[14];
  p.Wc3 = (const float*)d_in[15];
  p.bc3 = (const float*)d_in[16];
  p.W2  = (const float*)d_in[17];
  p.b2  = (const float*)d_in[18];
  p.rowptr = rowptr; p.invdeg = invdeg; p.csr = csr; p.ebuf = ebuf;
  p.bins = binsbuf; p.bcur = binsbuf + 128; p.bar = barptr;
  p.Wt1 = Wt1; p.Wt2 = Wt2; p.T729 = T729; p.M5T = M5T; p.beta5 = beta5;
  p.Sbuf = Sbuf; p.c5 = c5; p.Gbuf = Gbuf; p.Wg = Wg; p.bg = bg; p.c32 = c32;
  p.yzA = yzA; p.yzB = yzB; p.hA = hA; p.wbuf = wbuf; p.s1 = s1buf; p.s2 = s2buf;
  p.dout = (float*)d_out;
  p.E = E; p.N = N;

  // Grid sized to guaranteed co-residency (deadlock-free manual barrier).
  static int s_grid = 0;
  if (s_grid == 0) {
    int occ = 0;
    hipError_t e = hipOccupancyMaxActiveBlocksPerMultiprocessor(&occ, k_mega,
                                                                256, 0);
    if (e != hipSuccess || occ < 1) occ = 3;  // conservative fallback
    long g = (long)occ * 256;                 // 256 CUs on MI355X
    if (g > 2048) g = 2048;
    s_grid = (int)g;
  }

  (void)hipMemsetAsync(barptr, 0, 4, stream);  // barrier counter starts at 0
  hipLaunchKernelGGL(k_mega, dim3(s_grid), dim3(256), 0, stream, p);
}

// Round 8
// 278.633 us; speedup vs baseline: 7.2321x; 3.1593x over previous
//
#include <hip/hip_runtime.h>

#define NN 20000
#define NE 640000
#define NBUK 79  // ceil(20000/256) buckets of 256 nodes

// Self-probe: int64 edge data (values < 2^31) has every odd int32 word == 0.
__device__ __forceinline__ int probe_stride(const int* __restrict__ ei32) {
  int lane = threadIdx.x & 63;
  int v = ei32[2 * lane + 1];
  unsigned long long nz = __ballot(v != 0);
  return (nz == 0ull) ? 2 : 1;
}

__device__ __forceinline__ bool maskB(int var, int o2, int o1) {
  int s = o2 + o1;
  switch (var) {
    case 0: return (o2 >= 0) && (s >= 0);
    case 1: return s >= -1;
    case 3: return s <= 1;
    case 4: return (o2 <= 0) && (s <= 0);
    default: return true;
  }
}

// ============================ PHASE A1 =======================================
// blocks [0,151): weight setup (T729, beta5, Wt1, Wt2, Sbuf, c5)
// blocks [151,308): edge histogram -> PRIVATE rows bhist[u][79] (plain stores,
//   no zero-init, no atomics — R8: kills the memset dispatch + bcur atomics).
__global__ __launch_bounds__(256) void k_phaseA1(
    const int* __restrict__ ei, int* __restrict__ bhist,
    const float* __restrict__ Wc1, const float* __restrict__ Wc2,
    const float* __restrict__ Wc3, const float* __restrict__ bc1,
    const float* __restrict__ bc2, const float* __restrict__ bc3,
    const float* __restrict__ Wl1, const float* __restrict__ Wr1,
    const float* __restrict__ Wl2, const float* __restrict__ Wr2,
    const float* __restrict__ bl2,
    float* __restrict__ T729, float* __restrict__ beta5,
    float* __restrict__ Wt1, float* __restrict__ Wt2,
    float* __restrict__ Sbuf, float* __restrict__ c5,
    int* __restrict__ rowptr, int E, int N) {
  __shared__ float smem[6336];  // max branch: T729 (576+5184+576)
  int b = blockIdx.x, tid = threadIdx.x;
  if (b >= 151) {
    // ---- histogram (private row, no global atomics) ----
    int* lb = (int*)smem;
    int st = probe_stride(ei);
    for (int i = tid; i < NBUK; i += 256) lb[i] = 0;
    __syncthreads();
    int u = b - 151;
    int e0 = u * 4096;
#pragma unroll
    for (int t = 0; t < 16; ++t) {
      int e = e0 + t * 256 + tid;
      if (e < E) atomicAdd(&lb[ei[(size_t)(E + e) * st] >> 8], 1);
    }
    __syncthreads();
    for (int i = tid; i < NBUK; i += 256) bhist[u * NBUK + i] = lb[i];
    return;
  }
  int s = b;
  if (s == 0) {
    // ---- conv composite T729 ----
    float* W3  = smem;         // 576
    float* S9s = smem + 576;   // 5184
    float* W1s = smem + 5760;  // 576
    if (tid == 0) rowptr[N] = E;
    for (int e = tid; e < 576; e += 256) { W3[e] = Wc3[e]; W1s[e] = Wc1[e]; }
    __syncthreads();
    for (int bb = tid; bb < 576; bb += 256) {
      float acc[9];
#pragma unroll
      for (int a = 0; a < 9; ++a) acc[a] = 0.0f;
#pragma unroll 4
      for (int o = 0; o < 64; ++o) {
        float w2 = Wc2[o * 576 + bb];
#pragma unroll
        for (int a = 0; a < 9; ++a) acc[a] += W3[o * 9 + a] * w2;
      }
#pragma unroll
      for (int a = 0; a < 9; ++a) S9s[a * 576 + bb] = acc[a];
    }
    __syncthreads();
    for (int c = tid; c < 729; c += 256) {
      int kx0  = c % 3;
      int dl1e = (c / 3) % 3;
      int dl2e = (c / 9) % 3;
      int ky0  = (c / 27) % 3;
      int ky1  = (c / 81) % 3;
      int ky2  = c / 243;
      const float* s9 = &S9s[(ky2 * 3 + dl2e) * 576 + ky1 * 3 + dl1e];
      const float* w1 = &W1s[ky0 * 3 + kx0];
      float t = 0.0f;
#pragma unroll 8
      for (int i = 0; i < 64; ++i) t += s9[i * 9] * w1[i * 9];
      T729[c] = t;
    }
  } else if (s <= 5) {
    // ---- boundary beta vectors ----
    float* S2   = smem;          // 576
    float* W3b  = smem + 576;    // 576
    float* B2   = smem + 1152;   // 64
    float* part = smem + 1216;   // 256
    int var = s - 1;
    for (int e = tid; e < 576; e += 256) {
      int o = e / 9, r = e - o * 9;
      float t = 0.0f;
      for (int i = 0; i < 64; ++i) t += Wc2[o * 576 + i * 9 + r] * bc1[i];
      S2[e] = t;
      W3b[e] = Wc3[e];
    }
    if (tid < 64) B2[tid] = bc2[tid];
    __syncthreads();
    int u = tid & 63, oc = tid >> 6;
    float acc = 0.0f;
    for (int ky2 = 0; ky2 < 3; ++ky2) {
      int o2 = ky2 - 1;
      bool okA = (var == 0) ? (o2 >= 0) : (var == 4) ? (o2 <= 0) : true;
      if (!okA) continue;
      for (int dl2 = -1; dl2 <= 1; ++dl2) {
        int p = u + dl2; if ((unsigned)p >= 64u) continue;
        float sel[9];
#pragma unroll
        for (int ky1 = 0; ky1 < 3; ++ky1) {
          int o1 = ky1 - 1;
          bool mb = maskB(var, o2, o1);
#pragma unroll
          for (int dl1 = -1; dl1 <= 1; ++dl1) {
            int pq = p + dl1;
            sel[ky1 * 3 + dl1 + 1] = (mb && (unsigned)pq < 64u) ? 1.0f : 0.0f;
          }
        }
#pragma unroll 4
        for (int oo = 0; oo < 16; ++oo) {
          int o = oc * 16 + oo;
          float inner = B2[o];
#pragma unroll
          for (int r = 0; r < 9; ++r) inner += S2[o * 9 + r] * sel[r];
          acc += W3b[o * 9 + ky2 * 3 + (dl2 + 1)] * inner;
        }
      }
    }
    part[tid] = acc;
    __syncthreads();
    if (tid < 64) {
      beta5[var * 64 + tid] =
          bc3[0] + part[tid] + part[64 + tid] + part[128 + tid] + part[192 + tid];
    }
  } else {
    // ---- transposes + S-matrices + c5 ----
    int idx = (s - 6) * 256 + tid;  // 0..37119
    if (idx < 16384) {
      int w = idx >> 7, u = idx & 127;
      Wt1[idx] = (u < 64) ? Wl1[u * 128 + w] : Wr1[(u - 64) * 128 + w];
    } else if (idx < 24576) {
      int t = idx - 16384;
      int w = t >> 7, u = t & 127;
      Wt2[t] = (u < 64) ? Wl2[u * 64 + w] : Wr2[(u - 64) * 64 + w];
    } else if (idx < 36864) {
      // S2 = P·P, S1 = Q·P + P·Q, S0 = Q·Q  with P=Wl2^T, Q=Wr2^T.
      int t2 = idx - 24576;
      int m = t2 >> 12, e = t2 & 4095;
      int i = e >> 6, j = e & 63;
      float acc = 0.0f;
#pragma unroll 4
      for (int k = 0; k < 64; ++k) {
        float wlj = Wl2[j * 64 + k], wrj = Wr2[j * 64 + k];
        float wli = Wl2[k * 64 + i], wri = Wr2[k * 64 + i];
        if (m == 0) acc += wli * wlj;
        else if (m == 1) acc += wri * wlj + wli * wrj;
        else acc += wri * wrj;
      }
      Sbuf[t2] = acc;
    } else if (idx < 36928) {
      // c5 = bl2^T (P + Q + I)
      int j = idx - 36864;
      float acc = bl2[j];
      for (int i = 0; i < 64; ++i)
        acc += bl2[i] * (Wl2[j * 64 + i] + Wr2[j * 64 + i]);
      c5[j] = acc;
    }
  }
}

// ============================ PHASE A2 =======================================
// blocks [0,157): edge partition. Bucket base + within-bucket offset both
//   derived from bhist (deterministic, no bcur atomics).
// blocks [157,219): M5T | [219,252): G-matrices | [252,1502): sage1 GEMM
__global__ __launch_bounds__(256) void k_phaseA2(
    const float* __restrict__ X, const float* __restrict__ Wt1,
    float* __restrict__ yzA,
    const int* __restrict__ ei, const int* __restrict__ bhist,
    unsigned long long* __restrict__ ebuf,
    const float* __restrict__ T729, float* __restrict__ M5T,
    const float* __restrict__ Sbuf, const float* __restrict__ c5,
    const float* __restrict__ Wl3, const float* __restrict__ Wr3,
    const float* __restrict__ bl3, float* __restrict__ Gbuf,
    float* __restrict__ c32, int E, int N) {
  __shared__ float smem[2048];  // max branch: gemm Xs (16x128)
  int b = blockIdx.x, tid = threadIdx.x;
  if (b < 157) {
    // ---- partition: bases from bhist column sums ----
    int* lcnt  = (int*)smem;          // 79 (intra-block edge ranks)
    int* lbase = (int*)smem + 128;    // 79 (global write base per bucket)
    int* sscan = (int*)smem + 256;    // 128
    int st = probe_stride(ei);
    for (int i = tid; i < NBUK; i += 256) lcnt[i] = 0;
    int tot = 0, myoff = 0;
    if (tid < NBUK) {
      for (int v = 0; v < 157; ++v) {
        int h = bhist[v * NBUK + tid];
        tot += h;
        if (v < b) myoff += h;
      }
    }
    if (tid < 128) sscan[tid] = (tid < NBUK) ? tot : 0;
    __syncthreads();
    for (int off = 1; off < 128; off <<= 1) {
      int v = 0;
      if (tid < 128 && tid >= off) v = sscan[tid - off];
      __syncthreads();
      if (tid < 128) sscan[tid] += v;
      __syncthreads();
    }
    // sscan inclusive; exclusive = sscan - tot. Block's base = excl + myoff.
    if (tid < NBUK) lbase[tid] = (sscan[tid] - tot) + myoff;
    __syncthreads();
    int e0 = b * 4096;
    int srcv[16], dstv[16], lrank[16], bk[16];
    int n = 0;
#pragma unroll
    for (int t = 0; t < 16; ++t) {
      int e = e0 + t * 256 + tid;
      if (e < E) {
        int sv = ei[(size_t)e * st];
        int d = ei[(size_t)(E + e) * st];
        int bb = d >> 8;
        srcv[n] = sv; dstv[n] = d; bk[n] = bb;
        lrank[n] = atomicAdd(&lcnt[bb], 1);
        ++n;
      }
    }
    for (int t = 0; t < n; ++t) {
      int pos = lbase[bk[t]] + lrank[t];
      ebuf[pos] = ((unsigned long long)(unsigned)dstv[t] << 32) | (unsigned)srcv[t];
    }
  } else if (b < 219) {
    // ---- M5T ----
    float* Ts = smem;  // 729
    for (int e = tid; e < 729; e += 256) Ts[e] = T729[e];
    __syncthreads();
    int idx = (b - 157) * 256 + tid;
    if (idx >= 15680) return;
    int jw = idx % 7;
    int u  = (idx / 7) % 64;
    int d  = (idx / 448) % 7;
    int var = idx / 3136;
    int w = u + jw - 3;
    float acc = 0.0f;
    if (w >= 0 && w < 64) {
      for (int ky2 = 0; ky2 < 3; ++ky2) {
        int o2 = ky2 - 1;
        for (int ky1 = 0; ky1 < 3; ++ky1) {
          int o1 = ky1 - 1;
          if (!maskB(var, o2, o1)) continue;
          int o0 = (d - 3) - o2 - o1;
          if (o0 < -1 || o0 > 1) continue;
          int ky0 = o0 + 1;
          int cbase = ((ky2 * 3 + ky1) * 3 + ky0) * 27;
#pragma unroll
          for (int kx0 = 0; kx0 < 3; ++kx0) {
            int jq = jw - kx0;
            if ((unsigned)jq >= 5u) continue;
            int q = u + jq - 2;
            if ((unsigned)q >= 64u) continue;
#pragma unroll
            for (int dl2e = 0; dl2e < 3; ++dl2e) {
              int p = u + dl2e - 1;
              if ((unsigned)p >= 64u) continue;
              int dl1e = jq - dl2e;
              if ((unsigned)dl1e >= 3u) continue;
              acc += Ts[cbase + dl2e * 9 + dl1e * 3 + kx0];
            }
          }
        }
      }
    }
    if (d == 3 && jw == 3) acc += 1.0f;  // residual: out = conv(h) + h
    M5T[(var * 49 + d * 7 + jw) * 64 + u] = acc;
  } else if (b < 252) {
    // ---- G-matrices: G3=S2·P3, G2=S1·P3+S2·Q3, G1=S0·P3+S1·Q3, G0=S0·Q3 ----
    int bb = b - 219;
    if (bb < 32) {
      int idx = bb * 256 + tid;  // [kblk][t][j]
      int kblk = idx >> 11;
      int rem = idx & 2047;
      int t = rem >> 5, j = rem & 31;
      const float* S2p = Sbuf;
      const float* S1p = Sbuf + 4096;
      const float* S0p = Sbuf + 8192;
      const float* pa = (kblk == 0) ? S2p : (kblk == 1) ? S1p : (kblk == 2) ? S0p : nullptr;
      const float* pb = (kblk == 1) ? S2p : (kblk == 2) ? S1p : (kblk == 3) ? S0p : nullptr;
      float acc = 0.0f;
#pragma unroll 4
      for (int k = 0; k < 64; ++k) {
        if (pa) acc += pa[t * 64 + k] * Wl3[j * 64 + k];
        if (pb) acc += pb[t * 64 + k] * Wr3[j * 64 + k];
      }
      Gbuf[idx] = acc;
    } else if (tid < 32) {
      // c32 = c5^T (P3 + Q3) + bl3^T
      float acc = bl3[tid];
      for (int k = 0; k < 64; ++k)
        acc += c5[k] * (Wl3[tid * 64 + k] + Wr3[tid * 64 + k]);
      c32[tid] = acc;
    }
  } else {
    // ---- sage1 GEMM: yzA = x · Wt1  (C=128, K=128) ----
    constexpr int C = 128, K = 128, ROWS = 16, RPT = ROWS * C / 256;
    float* Xs = smem;
    int y0 = (b - 252) * ROWS;
    {
      const float4* src = (const float4*)(X + (size_t)y0 * K);
      float4* dst = (float4*)Xs;
#pragma unroll
      for (int v = 0; v < ROWS * K / 4 / 256; ++v)
        dst[v * 256 + tid] = src[v * 256 + tid];
    }
    __syncthreads();
    int u = tid % C;
    int rg = tid / C;
    float acc[RPT];
#pragma unroll
    for (int k = 0; k < RPT; ++k) acc[k] = 0.0f;
#pragma unroll 2
    for (int w0 = 0; w0 < K; w0 += 4) {
      float m0 = Wt1[(w0 + 0) * C + u];
      float m1 = Wt1[(w0 + 1) * C + u];
      float m2 = Wt1[(w0 + 2) * C + u];
      float m3 = Wt1[(w0 + 3) * C + u];
      const float* xs = &Xs[(rg * RPT) * K + w0];
#pragma unroll
      for (int k = 0; k < RPT; ++k) {
        float4 h = *(const float4*)(xs + k * K);
        acc[k] += m0 * h.x + m1 * h.y + m2 * h.z + m3 * h.w;
      }
    }
#pragma unroll
    for (int k = 0; k < RPT; ++k)
      yzA[(size_t)(y0 + rg * RPT + k) * C + u] = acc[k];
  }
}

// ============================ PHASE A3 =======================================
// blocks [0,79): per-bucket counting sort (bases/totals from bhist)
// blocks [79,112): Wg = W2^T·[G3|G2|G1|G0], bg = b2^T·[...]
__global__ __launch_bounds__(256) void k_phaseA3(
    const unsigned long long* __restrict__ ebuf, const int* __restrict__ bhist,
    int* __restrict__ rowptr, float* __restrict__ invdeg,
    int* __restrict__ csr,
    const float* __restrict__ Gbuf, const float* __restrict__ W2,
    const float* __restrict__ b2, float* __restrict__ Wg,
    float* __restrict__ bg, int N) {
  __shared__ int smem[772];  // lcnt 256 | lcur 256 | wsum 4 | sscan 128 | tots 128
  int b = blockIdx.x, tid = threadIdx.x;
  if (b < NBUK) {
    int* lcnt  = smem;
    int* lcur  = smem + 256;
    int* wsum  = smem + 512;
    int* sscan = smem + 516;
    int* tots  = smem + 644;
    int tot = 0;
    if (tid < NBUK)
      for (int v = 0; v < 157; ++v) tot += bhist[v * NBUK + tid];
    if (tid < 128) { tots[tid] = (tid < NBUK) ? tot : 0; sscan[tid] = tots ? ((tid < NBUK) ? tot : 0) : 0; }
    __syncthreads();
    for (int off = 1; off < 128; off <<= 1) {
      int v = 0;
      if (tid < 128 && tid >= off) v = sscan[tid - off];
      __syncthreads();
      if (tid < 128) sscan[tid] += v;
      __syncthreads();
    }
    if (tid < 128) sscan[tid] -= tots[tid];  // exclusive prefix
    __syncthreads();
    int base = sscan[b];
    int n = tots[b];
    lcnt[tid] = 0;
    __syncthreads();
    for (int e = tid; e < n; e += 256) {
      int d = (int)(ebuf[base + e] >> 32);
      atomicAdd(&lcnt[d - (b << 8)], 1);
    }
    __syncthreads();
    int c = lcnt[tid];
    int lane = tid & 63, wid = tid >> 6;
    int s = c;
#pragma unroll
    for (int off = 1; off < 64; off <<= 1) {
      int v = __shfl_up(s, off, 64);
      if (lane >= off) s += v;
    }
    if (lane == 63) wsum[wid] = s;
    __syncthreads();
    int woff = 0;
    for (int w = 0; w < wid; ++w) woff += wsum[w];
    int pref = woff + s - c;  // exclusive
    int gnode = (b << 8) + tid;
    if (gnode < N) {
      rowptr[gnode] = base + pref;
      invdeg[gnode] = 1.0f / (float)(c < 1 ? 1 : c);
    }
    lcur[tid] = pref;
    __syncthreads();
    for (int e = tid; e < n; e += 256) {
      unsigned long long pk = ebuf[base + e];
      int d = (int)(pk >> 32);
      int pos = atomicAdd(&lcur[d - (b << 8)], 1);
      csr[base + pos] = (int)(unsigned)pk;
    }
  } else {
    int bb = b - NBUK;
    if (bb < 32) {
      int idx = bb * 256 + tid;  // Wg[w*128+u]
      int w = idx >> 7, u = idx & 127;
      int kblk = u >> 5, j = u & 31;
      const float* gp = Gbuf + kblk * 2048 + j;
      float acc = 0.0f;
#pragma unroll 4
      for (int t = 0; t < 64; ++t) acc += W2[t * 64 + w] * gp[t * 32];
      Wg[idx] = acc;
    } else if (tid < 128) {
      int kblk = tid >> 5, j = tid & 31;
      const float* gp = Gbuf + kblk * 2048 + j;
      float acc = 0.0f;
      for (int t = 0; t < 64; ++t) acc += b2[t] * gp[t * 32];
      bg[tid] = acc;
    }
  }
}

// ------------------- fused mean-aggregation + GEMM --------------------------
template <int C>
__global__ __launch_bounds__(256) void k_fused(const float* __restrict__ yzin,
                                               const int* __restrict__ csr,
                                               const int* __restrict__ rowptr,
                                               const float* __restrict__ invdeg,
                                               const float* __restrict__ bl,
                                               const float* __restrict__ Wt,
                                               float* __restrict__ out, int N) {
  constexpr int FV = 16;
  constexpr int G  = 4;
  constexpr int S4 = 32;
  constexpr int CAP = 64;
  __shared__ int idxs[16 * CAP];
  __shared__ float htile[16 * 64];
  int tid = threadIdx.x;
  int w = tid >> 6, lane = tid & 63;
  int base = blockIdx.x * 16;
  int beg_r[4], m_r[4], end_r[4];
#pragma unroll
  for (int rr = 0; rr < 4; ++rr) {
    int node = base + w * 4 + rr;
    int beg = rowptr[node], end = rowptr[node + 1];
    beg_r[rr] = beg; end_r[rr] = end;
    int cnt = end - beg;
    int m = cnt < CAP ? cnt : CAP;
    m_r[rr] = m;
    int* my = &idxs[(w * 4 + rr) * CAP];
    for (int k = lane; k < m; k += 64) my[k] = csr[beg + k];
  }
  __syncthreads();
  int g = lane / FV, f = lane % FV;
  const float4* yz4 = (const float4*)yzin;
#pragma unroll
  for (int rr = 0; rr < 4; ++rr) {
    int node = base + w * 4 + rr;
    const int* my = &idxs[(w * 4 + rr) * CAP];
    int m = m_r[rr];
    float a0x=0,a0y=0,a0z=0,a0w=0, a1x=0,a1y=0,a1z=0,a1w=0;
    float a2x=0,a2y=0,a2z=0,a2w=0, a3x=0,a3y=0,a3z=0,a3w=0;
    int j = g;
    for (; j + 3 * G < m; j += 4 * G) {
      int s0 = my[j], s1 = my[j + G], s2 = my[j + 2 * G], s3 = my[j + 3 * G];
      float4 v0 = yz4[(size_t)s0 * S4 + f];
      float4 v1 = yz4[(size_t)s1 * S4 + f];
      float4 v2 = yz4[(size_t)s2 * S4 + f];
      float4 v3 = yz4[(size_t)s3 * S4 + f];
      a0x += v0.x; a0y += v0.y; a0z += v0.z; a0w += v0.w;
      a1x += v1.x; a1y += v1.y; a1z += v1.z; a1w += v1.w;
      a2x += v2.x; a2y += v2.y; a2z += v2.z; a2w += v2.w;
      a3x += v3.x; a3y += v3.y; a3z += v3.z; a3w += v3.w;
    }
    for (; j < m; j += G) {
      int s0 = my[j];
      float4 v0 = yz4[(size_t)s0 * S4 + f];
      a0x += v0.x; a0y += v0.y; a0z += v0.z; a0w += v0.w;
    }
    for (int jj = beg_r[rr] + CAP + g; jj < end_r[rr]; jj += G) {
      int s0 = csr[jj];
      float4 v0 = yz4[(size_t)s0 * S4 + f];
      a0x += v0.x; a0y += v0.y; a0z += v0.z; a0w += v0.w;
    }
    float ax = (a0x + a1x) + (a2x + a3x);
    float ay = (a0y + a1y) + (a2y + a3y);
    float az = (a0z + a1z) + (a2z + a3z);
    float aw = (a0w + a1w) + (a2w + a3w);
#pragma unroll
    for (int mm = FV; mm < 64; mm <<= 1) {
      ax += __shfl_xor(ax, mm, 64);
      ay += __shfl_xor(ay, mm, 64);
      az += __shfl_xor(az, mm, 64);
      aw += __shfl_xor(aw, mm, 64);
    }
    if (g == 0) {
      float4 root = yz4[(size_t)node * S4 + FV + f];
      float4 bv = ((const float4*)bl)[f];
      float id = invdeg[node];
      float4 o;
      o.x = ax * id + bv.x + root.x;
      o.y = ay * id + bv.y + root.y;
      o.z = az * id + bv.z + root.z;
      o.w = aw * id + bv.w + root.w;
      ((float4*)htile)[(w * 4 + rr) * 16 + f] = o;
    }
  }
  __syncthreads();
  constexpr int RPT = 16 * C / 256;
  int u = tid % C, rg = tid / C;
  float acc[RPT];
#pragma unroll
  for (int k = 0; k < RPT; ++k) acc[k] = 0.0f;
#pragma unroll 2
  for (int w0 = 0; w0 < 64; w0 += 4) {
    float m0 = Wt[(w0 + 0) * C + u];
    float m1 = Wt[(w0 + 1) * C + u];
    float m2 = Wt[(w0 + 2) * C + u];
    float m3 = Wt[(w0 + 3) * C + u];
    const float* xs = &htile[(rg * RPT) * 64 + w0];
#pragma unroll
    for (int k = 0; k < RPT; ++k) {
      float4 h4 = *(const float4*)(xs + k * 64);
      acc[k] += m0 * h4.x + m1 * h4.y + m2 * h4.z + m3 * h4.w;
    }
  }
#pragma unroll
  for (int k = 0; k < RPT; ++k)
    out[(size_t)(base + rg * RPT + k) * C + u] = acc[k];
}

// ---------- fused conv-composite apply + (linear2 ∘ sage4-6 collapse) -------
// Output: wbuf[k][node][32], k=0..3 -> w3,w2,w1,w0 for the agg32 chain.
__global__ __launch_bounds__(256) void k_applyfused(
    const float* __restrict__ h, const float* __restrict__ M5T,
    const float* __restrict__ beta5, const float* __restrict__ Wg,
    const float* __restrict__ bg, float* __restrict__ wout, int N) {
  __shared__ float hs[22 * 70];
  __shared__ float htile[16 * 64];
  int tid = threadIdx.x;
  int bstart = blockIdx.x * 16;
  for (int idx = tid; idx < 22 * 70; idx += 256) {
    int row = idx / 70, col = idx - row * 70;
    int y = bstart - 3 + row;
    int ww = col - 3;
    float v = 0.0f;
    if ((unsigned)y < (unsigned)N && (unsigned)ww < 64u)
      v = h[(size_t)y * 64 + ww];
    hs[idx] = v;
  }
  __syncthreads();
  int u = tid & 63, g = tid >> 6;
  int lr0 = g * 4;
  int gstart = bstart + lr0;
  const float* basep = &hs[lr0 * 70 + u];
  bool interior = (gstart >= 2) && (gstart + 3 <= N - 3);
  if (interior) {
    float c[49];
#pragma unroll
    for (int t = 0; t < 49; ++t) c[t] = M5T[(2 * 49 + t) * 64 + u];
    float bet = beta5[2 * 64 + u];
    float acc[4];
#pragma unroll
    for (int k = 0; k < 4; ++k) acc[k] = bet;
#pragma unroll
    for (int rr = 0; rr < 10; ++rr) {
      float t7[7];
#pragma unroll
      for (int jw = 0; jw < 7; ++jw) t7[jw] = basep[rr * 70 + jw];
#pragma unroll
      for (int d = 0; d < 7; ++d) {
        int k = rr - d;
        if (k >= 0 && k < 4) {
#pragma unroll
          for (int jw = 0; jw < 7; ++jw) acc[k] += c[d * 7 + jw] * t7[jw];
        }
      }
    }
#pragma unroll
    for (int k = 0; k < 4; ++k) htile[(lr0 + k) * 64 + u] = acc[k];
  } else {
    for (int k = 0; k < 4; ++k) {
      int y = gstart + k;
      int var = (y == 0) ? 0 : (y == 1) ? 1 : (y == N - 2) ? 3 : (y == N - 1) ? 4 : 2;
      float acc = beta5[var * 64 + u];
      for (int d = 0; d < 7; ++d)
        for (int jw = 0; jw < 7; ++jw)
          acc += M5T[(var * 49 + d * 7 + jw) * 64 + u] * basep[(k + d) * 70 + jw];
      htile[(lr0 + k) * 64 + u] = acc;
    }
  }
  __syncthreads();
  int u2 = tid % 128, rg = tid / 128;
  float acc2[8];
  float bv = bg[u2];
#pragma unroll
  for (int k = 0; k < 8; ++k) acc2[k] = bv;
#pragma unroll 2
  for (int w0 = 0; w0 < 64; w0 += 4) {
    float m0 = Wg[(w0 + 0) * 128 + u2];
    float m1 = Wg[(w0 + 1) * 128 + u2];
    float m2 = Wg[(w0 + 2) * 128 + u2];
    float m3 = Wg[(w0 + 3) * 128 + u2];
    const float* xs = &htile[(rg * 8) * 64 + w0];
#pragma unroll
    for (int k = 0; k < 8; ++k) {
      float4 h4 = *(const float4*)(xs + k * 64);
      acc2[k] += m0 * h4.x + m1 * h4.y + m2 * h4.z + m3 * h4.w;
    }
  }
  int kb = u2 >> 5, jj = u2 & 31;
#pragma unroll
  for (int k = 0; k < 8; ++k) {
    int node = bstart + rg * 8 + k;
    wout[((size_t)kb * N + node) * 32 + jj] = acc2[k];
  }
}

// ------------------ standalone mean aggregation (agg3) ----------------------
template <int DH>
__global__ __launch_bounds__(256) void k_agg(const float* __restrict__ yz,
                                             const int* __restrict__ csr,
                                             const int* __restrict__ rowptr,
                                             const float* __restrict__ invdeg,
                                             const float* __restrict__ bl,
                                             float* __restrict__ out, int N) {
  constexpr int FV = DH / 4;
  constexpr int G  = 64 / FV;
  constexpr int S4 = DH / 2;
  constexpr int CAP = 256;
  __shared__ int idxs[4 * CAP];
  int wid = threadIdx.x >> 6, lane = threadIdx.x & 63;
  int node = blockIdx.x * 4 + wid;
  int beg = rowptr[node], end = rowptr[node + 1];
  int cnt = end - beg;
  int m = cnt < CAP ? cnt : CAP;
  int* my = &idxs[wid * CAP];
  for (int k = lane; k < m; k += 64) my[k] = csr[beg + k];
  __syncthreads();
  int g = lane / FV, f = lane % FV;
  const float4* yz4 = (const float4*)yz;
  float a0x=0,a0y=0,a0z=0,a0w=0, a1x=0,a1y=0,a1z=0,a1w=0;
  float a2x=0,a2y=0,a2z=0,a2w=0, a3x=0,a3y=0,a3z=0,a3w=0;
  int j = g;
  for (; j + 3 * G < m; j += 4 * G) {
    int s0 = my[j], s1 = my[j + G], s2 = my[j + 2 * G], s3 = my[j + 3 * G];
    float4 v0 = yz4[(size_t)s0 * S4 + f];
    float4 v1 = yz4[(size_t)s1 * S4 + f];
    float4 v2 = yz4[(size_t)s2 * S4 + f];
    float4 v3 = yz4[(size_t)s3 * S4 + f];
    a0x += v0.x; a0y += v0.y; a0z += v0.z; a0w += v0.w;
    a1x += v1.x; a1y += v1.y; a1z += v1.z; a1w += v1.w;
    a2x += v2.x; a2y += v2.y; a2z += v2.z; a2w += v2.w;
    a3x += v3.x; a3y += v3.y; a3z += v3.z; a3w += v3.w;
  }
  for (; j < m; j += G) {
    int s0 = my[j];
    float4 v0 = yz4[(size_t)s0 * S4 + f];
    a0x += v0.x; a0y += v0.y; a0z += v0.z; a0w += v0.w;
  }
  for (int jj = beg + CAP + g; jj < end; jj += G) {
    int s0 = csr[jj];
    float4 v0 = yz4[(size_t)s0 * S4 + f];
    a0x += v0.x; a0y += v0.y; a0z += v0.z; a0w += v0.w;
  }
  float ax = (a0x + a1x) + (a2x + a3x);
  float ay = (a0y + a1y) + (a2y + a3y);
  float az = (a0z + a1z) + (a2z + a3z);
  float aw = (a0w + a1w) + (a2w + a3w);
#pragma unroll
  for (int mm = FV; mm < 64; mm <<= 1) {
    ax += __shfl_xor(ax, mm, 64);
    ay += __shfl_xor(ay, mm, 64);
    az += __shfl_xor(az, mm, 64);
    aw += __shfl_xor(aw, mm, 64);
  }
  if (g == 0) {
    float4 root = yz4[(size_t)node * S4 + FV + f];
    float4 bv = ((const float4*)bl)[f];
    float id = invdeg[node];
    float4 o;
    o.x = ax * id + bv.x + root.x;
    o.y = ay * id + bv.y + root.y;
    o.z = az * id + bv.z + root.z;
    o.w = aw * id + bv.w + root.w;
    ((float4*)out)[(size_t)node * FV + f] = o;
  }
}

// ---- 32-wide mean aggregation + elementwise add: out = (A src)·invdeg + add [+ cvec]
__global__ __launch_bounds__(256) void k_agg32(
    const float* __restrict__ src, const int* __restrict__ csr,
    const int* __restrict__ rowptr, const float* __restrict__ invdeg,
    const float* __restrict__ add, const float* __restrict__ cvec,
    float* __restrict__ out, int N) {
  constexpr int FV = 8;    // float4 per 32-float row
  constexpr int G  = 8;    // neighbor-parallel groups per wave
  constexpr int CAP = 256;
  __shared__ int idxs[4 * CAP];
  int wid = threadIdx.x >> 6, lane = threadIdx.x & 63;
  int node = blockIdx.x * 4 + wid;
  int beg = rowptr[node], end = rowptr[node + 1];
  int cnt = end - beg;
  int m = cnt < CAP ? cnt : CAP;
  int* my = &idxs[wid * CAP];
  for (int k = lane; k < m; k += 64) my[k] = csr[beg + k];
  __syncthreads();
  int g = lane / FV, f = lane % FV;
  const float4* sr4 = (const float4*)src;
  float a0x=0,a0y=0,a0z=0,a0w=0, a1x=0,a1y=0,a1z=0,a1w=0;
  float a2x=0,a2y=0,a2z=0,a2w=0, a3x=0,a3y=0,a3z=0,a3w=0;
  int j = g;
  for (; j + 3 * G < m; j += 4 * G) {
    int s0 = my[j], s1 = my[j + G], s2 = my[j + 2 * G], s3 = my[j + 3 * G];
    float4 v0 = sr4[(size_t)s0 * FV + f];
    float4 v1 = sr4[(size_t)s1 * FV + f];
    float4 v2 = sr4[(size_t)s2 * FV + f];
    float4 v3 = sr4[(size_t)s3 * FV + f];
    a0x += v0.x; a0y += v0.y; a0z += v0.z; a0w += v0.w;
    a1x += v1.x; a1y += v1.y; a1z += v1.z; a1w += v1.w;
    a2x += v2.x; a2y += v2.y; a2z += v2.z; a2w += v2.w;
    a3x += v3.x; a3y += v3.y; a3z += v3.z; a3w += v3.w;
  }
  for (; j < m; j += G) {
    int s0 = my[j];
    float4 v0 = sr4[(size_t)s0 * FV + f];
    a0x += v0.x; a0y += v0.y; a0z += v0.z; a0w += v0.w;
  }
  for (int jj = beg + CAP + g; jj < end; jj += G) {
    int s0 = csr[jj];
    float4 v0 = sr4[(size_t)s0 * FV + f];
    a0x += v0.x; a0y += v0.y; a0z += v0.z; a0w += v0.w;
  }
  float ax = (a0x + a1x) + (a2x + a3x);
  float ay = (a0y + a1y) + (a2y + a3y);
  float az = (a0z + a1z) + (a2z + a3z);
  float aw = (a0w + a1w) + (a2w + a3w);
#pragma unroll
  for (int mm = FV; mm < 64; mm <<= 1) {
    ax += __shfl_xor(ax, mm, 64);
    ay += __shfl_xor(ay, mm, 64);
    az += __shfl_xor(az, mm, 64);
    aw += __shfl_xor(aw, mm, 64);
  }
  if (g == 0) {
    float4 av = ((const float4*)add)[(size_t)node * FV + f];
    float id = invdeg[node];
    float4 o;
    o.x = ax * id + av.x;
    o.y = ay * id + av.y;
    o.z = az * id + av.z;
    o.w = aw * id + av.w;
    if (cvec != nullptr) {
      float4 cv = ((const float4*)cvec)[f];
      o.x += cv.x; o.y += cv.y; o.z += cv.z; o.w += cv.w;
    }
    ((float4*)out)[(size_t)node * FV + f] = o;
  }
}

// ------------------------------- launcher -----------------------------------
extern "C" void kernel_launch(void* const* d_in, const int* in_sizes, int n_in,
                              void* d_out, int out_size, void* d_ws, size_t ws_size,
                              hipStream_t stream) {
  const int N = NN, E = NE;
  const float* x   = (const float*)d_in[0];
  const int*   ei  = (const int*)d_in[1];
  const float* Wl1 = (const float*)d_in[2];
  const float* bl1 = (const float*)d_in[3];
  const float* Wr1 = (const float*)d_in[4];
  const float* Wl2 = (const float*)d_in[5];
  const float* bl2 = (const float*)d_in[6];
  const float* Wr2 = (const float*)d_in[7];
  const float* Wl3 = (const float*)d_in[8];
  const float* bl3 = (const float*)d_in[9];
  const float* Wr3 = (const float*)d_in[10];
  const float* Wc1 = (const float*)d_in[11];
  const float* bc1 = (const float*)d_in[12];
  const float* Wc2 = (const float*)d_in[13];
  const float* bc2 = (const float*)d_in[14];
  const float* Wc3 = (const float*)d_in[15];
  const float* bc3 = (const float*)d_in[16];
  const float* W2  = (const float*)d_in[17];
  const float* b2  = (const float*)d_in[18];

  char* ws = (char*)d_ws;
  size_t off = 0;
  auto alloc = [&](size_t bytes) -> void* {
    off = (off + 255) & ~(size_t)255;
    void* p = ws + off;
    off += bytes;
    return p;
  };
  int*   rowptr  = (int*)alloc((size_t)(N + 1) * 4);
  float* invdeg  = (float*)alloc((size_t)N * 4);
  int*   csr     = (int*)alloc((size_t)E * 4);
  unsigned long long* ebuf = (unsigned long long*)alloc((size_t)E * 8);
  int*   bhist   = (int*)alloc(157 * NBUK * 4);  // per-block hist rows (no init)
  float* Wt1     = (float*)alloc(128 * 128 * 4);
  float* Wt2     = (float*)alloc(64 * 128 * 4);
  float* T729    = (float*)alloc(729 * 4);
  float* M5T     = (float*)alloc(15680 * 4);
  float* beta5   = (float*)alloc(320 * 4);
  float* Sbuf    = (float*)alloc(12288 * 4);
  float* c5      = (float*)alloc(64 * 4);
  float* Gbuf    = (float*)alloc(8192 * 4);
  float* Wg      = (float*)alloc(8192 * 4);
  float* bg      = (float*)alloc(128 * 4);
  float* c32     = (float*)alloc(32 * 4);
  float* yzA     = (float*)alloc((size_t)N * 128 * 4);
  float* yzB     = (float*)alloc((size_t)N * 128 * 4);
  float* hA      = (float*)alloc((size_t)N * 64 * 4);
  float* wbuf    = (float*)alloc((size_t)4 * N * 32 * 4);
  float* s1buf   = (float*)alloc((size_t)N * 32 * 4);
  float* s2buf   = (float*)alloc((size_t)N * 32 * 4);
  (void)ws_size; (void)in_sizes; (void)n_in; (void)out_size;

  const int gG = N / 16;  // 1250
  const int gA = N / 4;   // 5000

  // A1: setup(151) || hist(157)  [no memset needed: bhist rows fully written]
  k_phaseA1<<<308, 256, 0, stream>>>(ei, bhist, Wc1, Wc2, Wc3, bc1, bc2, bc3,
                                     Wl1, Wr1, Wl2, Wr2, bl2,
                                     T729, beta5, Wt1, Wt2, Sbuf, c5,
                                     rowptr, E, N);
  // A2: part(157) || m5(62) || setupG(33) || sage1-GEMM(1250)
  k_phaseA2<<<1502, 256, 0, stream>>>(x, Wt1, yzA, ei, bhist, ebuf,
                                      T729, M5T, Sbuf, c5, Wl3, Wr3, bl3,
                                      Gbuf, c32, E, N);
  // A3: sortb(79) || setupWg(33)
  k_phaseA3<<<112, 256, 0, stream>>>(ebuf, bhist, rowptr, invdeg, csr,
                                     Gbuf, W2, b2, Wg, bg, N);

  // [agg1 + sage2-transform]
  k_fused<128><<<gG, 256, 0, stream>>>(yzA, csr, rowptr, invdeg, bl1, Wt2, yzB, N);
  // [agg2 + sage3-transform]
  k_fused<128><<<gG, 256, 0, stream>>>(yzB, csr, rowptr, invdeg, bl2, Wt2, yzA, N);
  // agg3 -> hA (conv input)
  k_agg<64><<<gA, 256, 0, stream>>>(yzA, csr, rowptr, invdeg, bl2, hA, N);
  // [conv-composite + residual + linear2 + sage4-6 weight collapse] -> w3|w2|w1|w0
  k_applyfused<<<gG, 256, 0, stream>>>(hA, M5T, beta5, Wg, bg, wbuf, N);
  // collapsed sage4-6: out = A(A(A w3 + w2) + w1) + w0 + c32
  const float* w3  = wbuf;
  const float* w2p = wbuf + (size_t)N * 32;
  const float* w1p = wbuf + (size_t)2 * N * 32;
  const float* w0p = wbuf + (size_t)3 * N * 32;
  k_agg32<<<gA, 256, 0, stream>>>(w3, csr, rowptr, invdeg, w2p, nullptr, s1buf, N);
  k_agg32<<<gA, 256, 0, stream>>>(s1buf, csr, rowptr, invdeg, w1p, nullptr, s2buf, N);
  k_agg32<<<gA, 256, 0, stream>>>(s2buf, csr, rowptr, invdeg, w0p, c32, (float*)d_out, N);
}